// Round 7
// baseline (14509.126 us; speedup 1.0000x reference)
//
#include <hip/hip_runtime.h>
#include <hip/hip_bf16.h>
#include <math.h>

// SimplifiedCTM on MI355X — round 7: occupancy fix. Batch-over-B GEMMs
// (thread = (row, batch), weight broadcast, LDS-staged activations),
// combined q-projection weight precomputed once, preds written directly
// to d_out. f32 in / f32 out. ws = 12.25 MiB.

#define DEV __device__ __forceinline__
typedef const float* fp;
typedef const float4* f4p;

#define B_   16
#define P_   196
#define D_   512
#define H_   8
#define HD_  64
#define N_   2048
#define M_   25
#define SA_  512
#define SO_  1024
#define O_   1000
#define T_   16

DEV float sigmf(float x){ return 1.0f / (1.0f + expf(-x)); }
DEV float wred(float v) { for (int m = 32; m; m >>= 1) v += __shfl_xor(v, m); return v; }
DEV float f4dot(float4 a, float4 b) { return a.x*b.x + a.y*b.y + a.z*b.z + a.w*b.w; }

DEV float breduce_sum(float v, float* red) {
  int t = threadIdx.x;
  red[t] = v; __syncthreads();
  for (int s = blockDim.x >> 1; s > 0; s >>= 1) {
    if (t < s) red[t] += red[t + s];
    __syncthreads();
  }
  float r = red[0]; __syncthreads();
  return r;
}
DEV float breduce_max(float v, float* red) {
  int t = threadIdx.x;
  red[t] = v; __syncthreads();
  for (int s = blockDim.x >> 1; s > 0; s >>= 1) {
    if (t < s) red[t] = fmaxf(red[t], red[t + s]);
    __syncthreads();
  }
  float r = red[0]; __syncthreads();
  return r;
}

// ---- P1a: conv-as-GEMM. grid (196 pgrp x 4 rgrp). 16 patches staged/block. ----
__global__ __launch_bounds__(256) void k_patch_mm(fp x, fp conv_w, fp conv_b, float* ptraw) {
  int pg = blockIdx.x >> 2, rg = blockIdx.x & 3;
  int bp0 = pg * 16;
  int tid = threadIdx.x;
  __shared__ float patch[16][772];
  for (int pi = 0; pi < 16; pi++) {
    int bp = bp0 + pi, b = bp / P_, p = bp % P_;
    int ph = p / 14, pw = p % 14;
    for (int j = tid; j < 768; j += 256) {
      int ci = j >> 8, r = j & 255, qi = r >> 4, qj = r & 15;
      patch[pi][j] = x[((size_t)(b*3 + ci)*224 + (ph*16 + qi))*224 + (pw*16 + qj)];
    }
  }
  __syncthreads();
  int r_loc = tid >> 4, pi = tid & 15;
  for (int rr = 0; rr < 8; rr++) {
    int r = rg*128 + rr*16 + r_loc;
    const float* wr = conv_w + (size_t)r*768;
    float acc = conv_b[r];
    for (int k = 0; k < 768; k += 4)
      acc += f4dot(*(f4p)(wr + k), *(f4p)(&patch[pi][k]));
    ptraw[(size_t)(bp0 + pi)*D_ + r] = acc;
  }
}

// ---- P1b: LN + pos over ptraw rows (in-place). grid 196, wave per 4 rows. ----
__global__ __launch_bounds__(256) void k_pln(float* pt, fp g, fp bb, fp pos) {
  int bp0 = blockIdx.x * 16;
  int tid = threadIdx.x, wave = tid >> 6, lane = tid & 63;
  for (int i = 0; i < 4; i++) {
    int bp = bp0 + wave*4 + i;
    int p = bp % P_;
    float* row = pt + (size_t)bp*D_;
    float4 v0 = *(f4p)(row + lane*8);
    float4 v1 = *(f4p)(row + lane*8 + 4);
    float s = v0.x+v0.y+v0.z+v0.w + v1.x+v1.y+v1.z+v1.w;
    float q = f4dot(v0,v0) + f4dot(v1,v1);
    s = wred(s); q = wred(q);
    float mu = s / (float)D_;
    float var = q / (float)D_ - mu*mu;
    float rstd = 1.f / sqrtf(var + 1e-5f);
    for (int j = 0; j < 8; j++) {
      int c = lane*8 + j;
      float v = (j < 4) ? ((const float*)&v0)[j] : ((const float*)&v1)[j-4];
      row[c] = (v - mu)*rstd*g[c] + bb[c] + pos[p*D_ + c];
    }
  }
}

// ---- P2a: kvraw = pt @ kv_w.T + kv_b. grid (196 x 4). ----
__global__ __launch_bounds__(256) void k_kv_mm(const float* pt, fp kv_w, fp kv_b, float* kvraw) {
  int pg = blockIdx.x >> 2, rg = blockIdx.x & 3;
  int bp0 = pg * 16;
  int tid = threadIdx.x;
  __shared__ float xin[16][516];
  for (int idx = tid; idx < 16*512; idx += 256) {
    int bb = idx >> 9, c = idx & 511;
    xin[bb][c] = pt[(size_t)(bp0 + bb)*D_ + c];
  }
  __syncthreads();
  int r_loc = tid >> 4, bl = tid & 15;
  for (int rr = 0; rr < 8; rr++) {
    int r = rg*128 + rr*16 + r_loc;
    const float* wr = kv_w + (size_t)r*512;
    float acc = kv_b[r];
    for (int k = 0; k < 512; k += 4)
      acc += f4dot(*(f4p)(wr + k), *(f4p)(&xin[bl][k]));
    kvraw[(size_t)(bp0 + bl)*D_ + r] = acc;
  }
}

// ---- P2b: LN in-place on kvb rows. grid 196. ----
__global__ __launch_bounds__(256) void k_kvln(float* kv, fp g, fp bb) {
  int bp0 = blockIdx.x * 16;
  int tid = threadIdx.x, wave = tid >> 6, lane = tid & 63;
  for (int i = 0; i < 4; i++) {
    int bp = bp0 + wave*4 + i;
    float* row = kv + (size_t)bp*D_;
    float4 v0 = *(f4p)(row + lane*8);
    float4 v1 = *(f4p)(row + lane*8 + 4);
    float s = v0.x+v0.y+v0.z+v0.w + v1.x+v1.y+v1.z+v1.w;
    float q = f4dot(v0,v0) + f4dot(v1,v1);
    s = wred(s); q = wred(q);
    float mu = s / (float)D_;
    float var = q / (float)D_ - mu*mu;
    float rstd = 1.f / sqrtf(var + 1e-5f);
    for (int j = 0; j < 8; j++) {
      int c = lane*8 + j;
      float v = (j < 4) ? ((const float*)&v0)[j] : ((const float*)&v1)[j-4];
      row[c] = (v - mu)*rstd*g[c] + bb[c];
    }
  }
}

// ---- P3: W_qc[i][s] = 0.125 * sum_j wq[i][j] q_w[j][s]. grid (32,32). ----
__global__ __launch_bounds__(256) void k_wqc(fp aw, fp q_w, float* W_qc) {
  int i0 = blockIdx.x * 16, s0 = blockIdx.y * 16;
  int tid = threadIdx.x, il = tid >> 4, sl = tid & 15;
  __shared__ float s_wq[16][129];
  __shared__ float s_qw[128][17];
  float acc = 0.f;
  for (int kc = 0; kc < 4; kc++) {
    int k0 = kc * 128;
    for (int idx = tid; idx < 2048; idx += 256) {
      int r = idx >> 7, c = idx & 127;
      s_wq[r][c] = aw[(size_t)(i0 + r)*512 + k0 + c];
    }
    for (int idx = tid; idx < 2048; idx += 256) {
      int r = idx >> 4, c = idx & 15;
      s_qw[r][c] = q_w[(size_t)(k0 + r)*512 + s0 + c];
    }
    __syncthreads();
    for (int kk = 0; kk < 128; kk++)
      acc += s_wq[il][kk] * s_qw[kk][sl];
    __syncthreads();
  }
  W_qc[(size_t)(i0 + il)*512 + s0 + sl] = 0.125f * acc;
}

// ---- P3b: bc[i] = 0.125 * (wq[i]·q_b + bq[i]). grid 2. ----
__global__ __launch_bounds__(256) void k_wqcb(fp aw, fp q_b, fp ab, float* bc) {
  int i = blockIdx.x * 256 + threadIdx.x;
  float acc = ab[i];
  for (int j = 0; j < 512; j++) acc += aw[(size_t)i*512 + j] * q_b[j];
  bc[i] = 0.125f * acc;
}

// ---- INIT ----
__global__ void k_init(fp start_state, fp start_trace, const int* oL, const int* oR,
                       float* act, float* trace, float* aa, float* ba, float* ao, float* bo) {
  int gid = blockIdx.x * 256 + threadIdx.x;
  if (gid < B_*N_*M_) {
    int bn = gid / M_, m = gid % M_;
    int n = bn % N_;
    trace[gid] = start_trace[n*M_ + m];
  }
  if (gid < B_*N_) act[gid] = start_state[gid & (N_-1)];
  if (gid < B_*SA_) { aa[gid] = 0.f; ba[gid] = 0.f; }
  if (gid < B_*SO_) {
    int s = gid & (SO_-1);
    ao[gid] = start_state[oL[s]] * start_state[oR[s]];
    bo[gid] = 1.0f;
  }
}

// ---- T1a: action sync -> sact_ws. grid 16. ----
__global__ __launch_bounds__(256) void k_sync1(const float* act, float* aa, float* ba,
                                               fp decay_a, const int* L, const int* R,
                                               float* sact_ws) {
  int b = blockIdx.x, tid = threadIdx.x;
  for (int cc = 0; cc < 2; cc++) {
    int s_ = tid + cc*256;
    float r = expf(-decay_a[s_]);
    float pair = act[b*N_ + L[s_]] * act[b*N_ + R[s_]];
    float a  = r*aa[b*SA_ + s_] + pair;
    float bt = r*ba[b*SA_ + s_] + 1.0f;
    aa[b*SA_ + s_] = a; ba[b*SA_ + s_] = bt;
    sact_ws[b*SA_ + s_] = a / sqrtf(bt);
  }
}

// ---- T1b: qh = sact @ W_qc.T + bc (scale folded). grid 32. ----
__global__ __launch_bounds__(256) void k_q(const float* sact_ws, const float* W_qc,
                                           const float* bc, float* qh) {
  int r0 = blockIdx.x * 16;
  int tid = threadIdx.x, r_loc = tid >> 4, b = tid & 15;
  __shared__ float s_x[16][516];
  for (int idx = tid; idx < 16*512; idx += 256) {
    int bb = idx >> 9, c = idx & 511;
    s_x[bb][c] = sact_ws[bb*SA_ + c];
  }
  __syncthreads();
  int r = r0 + r_loc;
  const float* wr = W_qc + (size_t)r*512;
  float acc = 0.f;
  for (int k = 0; k < 512; k += 4)
    acc += f4dot(*(f4p)(wr + k), *(f4p)(&s_x[b][k]));
  qh[b*D_ + r] = acc + bc[r];
}

// ---- T2: rank-space attention per (b,h): qt, scores, softmax, zz. ----
__global__ __launch_bounds__(256) void k_attn(const float* qh, const float* kvb,
                                              fp aw, fp ab, float* zz) {
  int b = blockIdx.x, h = blockIdx.y;
  int tid = threadIdx.x, wave = tid >> 6, lane = tid & 63;
  __shared__ float qhh[64];
  __shared__ float qt[512];
  __shared__ float sc[256];
  __shared__ float red[256];
  __shared__ float zpart[4][512];
  if (tid < 64) qhh[tid] = qh[b*D_ + h*HD_ + tid];
  __syncthreads();
  float acc0 = 0.f, acc1 = 0.f;
  for (int e = 0; e < HD_; e++) {
    float q = qhh[e];
    const float* ar = aw + (size_t)(512 + h*HD_ + e)*D_;
    acc0 += q * ar[tid];
    acc1 += q * ar[tid + 256];
  }
  qt[tid] = acc0; qt[tid + 256] = acc1;
  float kb = 0.f;
  for (int e = 0; e < HD_; e++) kb += qhh[e] * ab[512 + h*HD_ + e];
  __syncthreads();
  for (int p = wave*49; p < wave*49 + 49; p++) {
    const float* kvp = kvb + ((size_t)(b*P_ + p))*D_;
    float s = f4dot(*(f4p)(kvp + lane*4),       *(f4p)(qt + lane*4))
            + f4dot(*(f4p)(kvp + 256 + lane*4), *(f4p)(qt + 256 + lane*4));
    s = wred(s);
    if (lane == 0) sc[p] = s + kb;
  }
  __syncthreads();
  float v = (tid < P_) ? sc[tid] : -1e30f;
  float m = breduce_max(v, red);
  float e = (tid < P_) ? expf(sc[tid] - m) : 0.f;
  if (tid < P_) sc[tid] = e;
  float ssum = breduce_sum(e, red);
  float inv = 1.f / ssum;
  float4 z0 = {0,0,0,0}, z1 = {0,0,0,0};
  for (int p = wave*49; p < wave*49 + 49; p++) {
    const float* kvp = kvb + ((size_t)(b*P_ + p))*D_ + lane*8;
    float w = sc[p];
    float4 a = *(f4p)(kvp), c = *(f4p)(kvp + 4);
    z0.x += w*a.x; z0.y += w*a.y; z0.z += w*a.z; z0.w += w*a.w;
    z1.x += w*c.x; z1.y += w*c.y; z1.z += w*c.z; z1.w += w*c.w;
  }
  *(float4*)(&zpart[wave][lane*8])     = z0;
  *(float4*)(&zpart[wave][lane*8 + 4]) = z1;
  __syncthreads();
  for (int cc = 0; cc < 2; cc++) {
    int c = tid + cc*256;
    zz[((size_t)(b*H_ + h))*D_ + c] =
      (zpart[0][c] + zpart[1][c] + zpart[2][c] + zpart[3][c]) * inv;
  }
}

// ---- T2b: av = zz_h @ wv.T + bv. grid 32 (h = bid/4). ----
__global__ __launch_bounds__(256) void k_av(const float* zz, fp aw, fp ab, float* av_ws) {
  int r0 = blockIdx.x * 16, h = r0 >> 6;
  int tid = threadIdx.x, r_loc = tid >> 4, b = tid & 15;
  __shared__ float s_z[16][516];
  for (int idx = tid; idx < 16*512; idx += 256) {
    int bb = idx >> 9, c = idx & 511;
    s_z[bb][c] = zz[((size_t)(bb*H_ + h))*D_ + c];
  }
  __syncthreads();
  int r = r0 + r_loc;
  const float* wr = aw + (size_t)(1024 + r)*512;
  float acc = ab[1024 + r];
  for (int k = 0; k < 512; k += 4)
    acc += f4dot(*(f4p)(wr + k), *(f4p)(&s_z[b][k]));
  av_ws[b*D_ + r] = acc;
}

// ---- T2c: attn_o = av @ ow.T + ob. grid 32. ----
__global__ __launch_bounds__(256) void k_ao2(const float* av_ws, fp ow, fp ob, float* attn_o) {
  int r0 = blockIdx.x * 16;
  int tid = threadIdx.x, r_loc = tid >> 4, b = tid & 15;
  __shared__ float s_a[16][516];
  for (int idx = tid; idx < 16*512; idx += 256) {
    int bb = idx >> 9, c = idx & 511;
    s_a[bb][c] = av_ws[bb*D_ + c];
  }
  __syncthreads();
  int r = r0 + r_loc;
  const float* wr = ow + (size_t)r*512;
  float acc = ob[r];
  for (int k = 0; k < 512; k += 4)
    acc += f4dot(*(f4p)(wr + k), *(f4p)(&s_a[b][k]));
  attn_o[b*D_ + r] = acc;
}

// ---- T3: y = pre @ syn_w.T + syn_b. grid 256 (16 rows x 16 b / block). ----
__global__ __launch_bounds__(256) void k_syn(const float* attn_o, const float* act,
                                             fp syn_w, fp syn_b, float* y) {
  int r0 = blockIdx.x * 16;
  int tid = threadIdx.x, r_loc = tid >> 4, b = tid & 15;
  __shared__ float s_pre[16][260];
  int r = r0 + r_loc;
  const float* wr = syn_w + (size_t)r*2560;
  float acc = 0.f;
  for (int ch = 0; ch < 10; ch++) {
    int c0 = ch * 256;
    for (int bb = 0; bb < 16; bb++) {
      int k = c0 + tid;
      s_pre[bb][tid] = (k < 512) ? attn_o[bb*D_ + k] : act[bb*N_ + (k - 512)];
    }
    __syncthreads();
    for (int kk = 0; kk < 256; kk += 4)
      acc += f4dot(*(f4p)(wr + c0 + kk), *(f4p)(&s_pre[b][kk]));
    __syncthreads();
  }
  y[(size_t)b*4096 + r] = acc + syn_b[r];
}

// ---- T4: GLU + LN -> state. grid 16. ----
__global__ __launch_bounds__(256) void k_state(const float* y, fp g, fp bvec, float* state) {
  int b = blockIdx.x, tid = threadIdx.x;
  __shared__ float st[2048];
  __shared__ float red[256];
  float ls = 0.f, lq = 0.f;
  for (int ii = 0; ii < 8; ii++) {
    int c = ii*256 + tid;
    float a  = y[(size_t)b*4096 + c];
    float gg = y[(size_t)b*4096 + 2048 + c];
    float v = a * sigmf(gg);
    st[c] = v; ls += v; lq += v*v;
  }
  float S = breduce_sum(ls, red);
  float Q = breduce_sum(lq, red);
  float mu = S / (float)N_;
  float var = Q / (float)N_ - mu*mu;
  float rstd = 1.f / sqrtf(var + 1e-5f);
  for (int ii = 0; ii < 8; ii++) {
    int c = ii*256 + tid;
    state[b*N_ + c] = (st[c] - mu)*rstd*g[c] + bvec[c];
  }
}

// ---- T5: NLM per neuron; trace shift-append fused. grid 2048. ----
__global__ __launch_bounds__(256) void k_nlm(float* trace, const float* state,
                                             fp fc1_w, fp fc1_b, fp fc2_w, fp fc2_b,
                                             fp nlmT, float* act) {
  int n = blockIdx.x, tid = threadIdx.x;
  __shared__ float tr[B_][M_];
  __shared__ float uu[256][17];
  __shared__ float h1[128][17];
  __shared__ float vout[B_][2];
  for (int i = tid; i < B_*M_; i += 256) {
    int b = i / M_, m = i % M_;
    tr[b][m] = (m < M_-1) ? trace[((size_t)(b*N_ + n))*M_ + m + 1] : state[b*N_ + n];
  }
  __syncthreads();
  for (int i = tid; i < B_*M_; i += 256) {
    int b = i / M_, m = i % M_;
    trace[((size_t)(b*N_ + n))*M_ + m] = tr[b][m];
  }
  float w25[M_];
  for (int m = 0; m < M_; m++) w25[m] = fc1_w[((size_t)n*M_ + m)*256 + tid];
  float bias = fc1_b[n*256 + tid];
  for (int b = 0; b < B_; b++) {
    float u = bias;
    for (int m = 0; m < M_; m++) u += tr[b][m]*w25[m];
    uu[tid][b] = u;
  }
  __syncthreads();
  if (tid < 128) {
    for (int b = 0; b < B_; b++)
      h1[tid][b] = uu[tid][b] * sigmf(uu[tid + 128][b]);
  }
  __syncthreads();
  if (tid < 32) {
    int b = tid >> 1, o = tid & 1;
    float acc = fc2_b[n*2 + o];
    for (int hh = 0; hh < 128; hh++) acc += h1[hh][b] * fc2_w[((size_t)n*128 + hh)*2 + o];
    vout[b][o] = acc;
  }
  __syncthreads();
  if (tid < B_) {
    act[tid*N_ + n] = vout[tid][0] * sigmf(vout[tid][1]) / nlmT[0];
  }
}

// ---- T6a: out sync -> sout_ws. grid 16. ----
__global__ __launch_bounds__(256) void k_osync(const float* act, float* ao, float* bo,
                                               fp decay_o, const int* L, const int* R,
                                               float* sout_ws) {
  int b = blockIdx.x, tid = threadIdx.x;
  for (int cc = 0; cc < 4; cc++) {
    int s_ = tid + cc*256;
    float r = expf(-decay_o[s_]);
    float pair = act[b*N_ + L[s_]] * act[b*N_ + R[s_]];
    float a  = r*ao[b*SO_ + s_] + pair;
    float bt = r*bo[b*SO_ + s_] + 1.f;
    ao[b*SO_ + s_] = a; bo[b*SO_ + s_] = bt;
    sout_ws[b*SO_ + s_] = a / sqrtf(bt);
  }
}

// ---- T6b: preds (direct to d_out). grid (32 rgrp, 2 bgrp); 32r x 8b threads. ----
__global__ __launch_bounds__(256) void k_out(const float* sout_ws, fp out_w, fp out_b,
                                             float* out, int t) {
  int rb = blockIdx.x, bg = blockIdx.y;
  int tid = threadIdx.x, r_loc = tid >> 3, b_loc = tid & 7;
  __shared__ float s_sout[8][1028];
  for (int idx = tid; idx < 8*1024; idx += 256) {
    int bb = idx >> 10, c = idx & 1023;
    s_sout[bb][c] = sout_ws[(bg*8 + bb)*SO_ + c];
  }
  __syncthreads();
  int r = rb*32 + r_loc;
  if (r >= O_) return;
  int b = bg*8 + b_loc;
  const float* wr = out_w + (size_t)r*1024;
  float acc = out_b[r];
  for (int k = 0; k < 1024; k += 4)
    acc += f4dot(*(f4p)(wr + k), *(f4p)(&s_sout[b_loc][k]));
  out[((size_t)(b*O_ + r))*T_ + t] = acc;
}

// ---- T7: entropy from d_out preds. grid (16,16). ----
__global__ __launch_bounds__(256) void k_final(float* out) {
  int b = blockIdx.x, t = blockIdx.y, tid = threadIdx.x;
  __shared__ float red[256];
  float lm = -1e30f;
  for (int o = tid; o < O_; o += 256) lm = fmaxf(lm, out[((size_t)(b*O_ + o))*T_ + t]);
  float Mx = breduce_max(lm, red);
  float le = 0.f;
  for (int o = tid; o < O_; o += 256) le += expf(out[((size_t)(b*O_ + o))*T_ + t] - Mx);
  float S = breduce_sum(le, red);
  float lt = 0.f;
  for (int o = tid; o < O_; o += 256) {
    float pr = expf(out[((size_t)(b*O_ + o))*T_ + t] - Mx) / S;
    lt += pr * logf(pr + 1e-10f);
  }
  float E = breduce_sum(lt, red);
  if (tid == 0)
    out[(size_t)B_*O_*T_ + b*T_ + t] = -E / logf((float)O_);
}

extern "C" void kernel_launch(void* const* d_in, const int* in_sizes, int n_in,
                              void* d_out, int out_size, void* d_ws, size_t ws_size,
                              hipStream_t stream) {
  (void)in_sizes; (void)n_in; (void)out_size; (void)ws_size;
  fp x          = (fp)d_in[0];
  fp conv_w     = (fp)d_in[1];
  fp conv_b     = (fp)d_in[2];
  fp patch_ln_g = (fp)d_in[3];
  fp patch_ln_b = (fp)d_in[4];
  fp pos        = (fp)d_in[5];
  fp kv_w       = (fp)d_in[6];
  fp kv_b       = (fp)d_in[7];
  fp kv_ln_g    = (fp)d_in[8];
  fp kv_ln_b    = (fp)d_in[9];
  fp q_w        = (fp)d_in[10];
  fp q_b        = (fp)d_in[11];
  fp attn_in_w  = (fp)d_in[12];
  fp attn_in_b  = (fp)d_in[13];
  fp attn_out_w = (fp)d_in[14];
  fp attn_out_b = (fp)d_in[15];
  fp syn_w      = (fp)d_in[16];
  fp syn_b      = (fp)d_in[17];
  fp syn_ln_g   = (fp)d_in[18];
  fp syn_ln_b   = (fp)d_in[19];
  fp fc1_w      = (fp)d_in[20];
  fp fc1_b      = (fp)d_in[21];
  fp fc2_w      = (fp)d_in[22];
  fp fc2_b      = (fp)d_in[23];
  fp nlm_T      = (fp)d_in[24];
  fp start_state= (fp)d_in[25];
  fp start_trace= (fp)d_in[26];
  fp decay_a    = (fp)d_in[27];
  fp decay_o    = (fp)d_in[28];
  fp out_w      = (fp)d_in[29];
  fp out_b      = (fp)d_in[30];
  const int* act_left  = (const int*)d_in[31];
  const int* act_right = (const int*)d_in[32];
  const int* out_left  = (const int*)d_in[33];
  const int* out_right = (const int*)d_in[34];

  // ws: region X [0, 1605632) holds pt during precompute, then per-tick state
  // (written only after pt is dead). kvb panel follows. Total 12.25 MiB.
  float* ws = (float*)d_ws;
  float* pt     = ws;                          // precompute only
  float* act    = ws + 0;                      // 32768
  float* trace  = ws + 32768;                  // 819200
  float* aa     = ws + 851968;                 // 8192
  float* ba     = ws + 860160;                 // 8192
  float* ao     = ws + 868352;                 // 16384
  float* bo     = ws + 884736;                 // 16384
  float* qh     = ws + 901120;                 // 8192
  float* attn_o = ws + 909312;                 // 8192
  float* ysyn   = ws + 917504;                 // 65536
  float* state  = ws + 983040;                 // 32768
  float* zz     = ws + 1015808;                // 65536
  float* sact_ws= ws + 1081344;                // 8192
  float* av_ws  = ws + 1089536;                // 8192
  float* sout_ws= ws + 1097728;                // 16384
  float* W_qc   = ws + 1114112;                // 262144
  float* bc     = ws + 1376256;                // 512 -> 1376768 < 1605632
  float* kvb    = ws + 1605632;                // 1605632

  k_patch_mm<<<dim3(196*4), dim3(256), 0, stream>>>(x, conv_w, conv_b, pt);
  k_pln<<<dim3(196), dim3(256), 0, stream>>>(pt, patch_ln_g, patch_ln_b, pos);
  k_kv_mm<<<dim3(196*4), dim3(256), 0, stream>>>(pt, kv_w, kv_b, kvb);
  k_kvln<<<dim3(196), dim3(256), 0, stream>>>(kvb, kv_ln_g, kv_ln_b);
  // pt dead; safe to write W_qc / state region now.
  k_wqc<<<dim3(32, 32), dim3(256), 0, stream>>>(attn_in_w, q_w, W_qc);
  k_wqcb<<<dim3(2), dim3(256), 0, stream>>>(attn_in_w, q_b, attn_in_b, bc);
  k_init<<<dim3((B_*N_*M_ + 255)/256), dim3(256), 0, stream>>>(start_state, start_trace,
        out_left, out_right, act, trace, aa, ba, ao, bo);

  for (int t = 0; t < T_; t++) {
    k_sync1<<<dim3(B_), dim3(256), 0, stream>>>(act, aa, ba, decay_a, act_left, act_right, sact_ws);
    k_q<<<dim3(32), dim3(256), 0, stream>>>(sact_ws, W_qc, bc, qh);
    k_attn<<<dim3(B_, H_), dim3(256), 0, stream>>>(qh, kvb, attn_in_w, attn_in_b, zz);
    k_av<<<dim3(32), dim3(256), 0, stream>>>(zz, attn_in_w, attn_in_b, av_ws);
    k_ao2<<<dim3(32), dim3(256), 0, stream>>>(av_ws, attn_out_w, attn_out_b, attn_o);
    k_syn<<<dim3(256), dim3(256), 0, stream>>>(attn_o, act, syn_w, syn_b, ysyn);
    k_state<<<dim3(B_), dim3(256), 0, stream>>>(ysyn, syn_ln_g, syn_ln_b, state);
    k_nlm<<<dim3(N_), dim3(256), 0, stream>>>(trace, state, fc1_w, fc1_b, fc2_w, fc2_b,
                                              nlm_T, act);
    k_osync<<<dim3(B_), dim3(256), 0, stream>>>(act, ao, bo, decay_o, out_left, out_right, sout_ws);
    k_out<<<dim3(32, 2), dim3(256), 0, stream>>>(sout_ws, out_w, out_b, (float*)d_out, t);
  }
  k_final<<<dim3(B_, T_), dim3(256), 0, stream>>>((float*)d_out);
}

// Round 8
// 4886.353 us; speedup vs baseline: 2.9693x; 2.9693x over previous
//
#include <hip/hip_runtime.h>
#include <hip/hip_bf16.h>
#include <math.h>

// SimplifiedCTM on MI355X — round 8: revert k_syn to wave-coop (r7's broadcast-row
// mapping caused 13x overfetch + scratch spill, 750us/dispatch), wave-coop k_out.
// Rule: weights stream lane-across-K; batch reuse via register accumulators.

#define DEV __device__ __forceinline__
typedef const float* fp;
typedef const float4* f4p;

#define B_   16
#define P_   196
#define D_   512
#define H_   8
#define HD_  64
#define N_   2048
#define M_   25
#define SA_  512
#define SO_  1024
#define O_   1000
#define T_   16

DEV float sigmf(float x){ return 1.0f / (1.0f + expf(-x)); }
DEV float wred(float v) { for (int m = 32; m; m >>= 1) v += __shfl_xor(v, m); return v; }
DEV float f4dot(float4 a, float4 b) { return a.x*b.x + a.y*b.y + a.z*b.z + a.w*b.w; }

DEV float breduce_sum(float v, float* red) {
  int t = threadIdx.x;
  red[t] = v; __syncthreads();
  for (int s = blockDim.x >> 1; s > 0; s >>= 1) {
    if (t < s) red[t] += red[t + s];
    __syncthreads();
  }
  float r = red[0]; __syncthreads();
  return r;
}
DEV float breduce_max(float v, float* red) {
  int t = threadIdx.x;
  red[t] = v; __syncthreads();
  for (int s = blockDim.x >> 1; s > 0; s >>= 1) {
    if (t < s) red[t] = fmaxf(red[t], red[t + s]);
    __syncthreads();
  }
  float r = red[0]; __syncthreads();
  return r;
}

// ---- P1a: conv-as-GEMM. grid (196 x 4). 16 patches staged/block. ----
__global__ __launch_bounds__(256) void k_patch_mm(fp x, fp conv_w, fp conv_b, float* ptraw) {
  int pg = blockIdx.x >> 2, rg = blockIdx.x & 3;
  int bp0 = pg * 16;
  int tid = threadIdx.x, wave = tid >> 6, lane = tid & 63;
  __shared__ float patch[16][772];
  for (int pi = 0; pi < 16; pi++) {
    int bp = bp0 + pi, b = bp / P_, p = bp % P_;
    int ph = p / 14, pw = p % 14;
    for (int j = tid; j < 768; j += 256) {
      int ci = j >> 8, r = j & 255, qi = r >> 4, qj = r & 15;
      patch[pi][j] = x[((size_t)(b*3 + ci)*224 + (ph*16 + qi))*224 + (pw*16 + qj)];
    }
  }
  __syncthreads();
  // wave-coop: 32 rows/wave, 16 patches via register accumulators (2 passes of 8)
  for (int k = 0; k < 32; k++) {
    int r = rg*128 + wave*32 + k;
    const float* wr = conv_w + (size_t)r*768 + lane*4;
    float4 w0 = *(f4p)(wr), w1 = *(f4p)(wr + 256), w2 = *(f4p)(wr + 512);
    float cb = conv_b[r];
    for (int half = 0; half < 2; half++) {
      float pp[8];
      for (int pi = 0; pi < 8; pi++) {
        const float* pb = &patch[half*8 + pi][lane*4];
        pp[pi] = f4dot(w0, *(f4p)(pb)) + f4dot(w1, *(f4p)(pb + 256))
               + f4dot(w2, *(f4p)(pb + 512));
      }
      for (int pi = 0; pi < 8; pi++) {
        float s = wred(pp[pi]);
        if (lane == 0) ptraw[(size_t)(bp0 + half*8 + pi)*D_ + r] = s + cb;
      }
    }
  }
}

// ---- P1b: LN + pos (in-place). grid 196. ----
__global__ __launch_bounds__(256) void k_pln(float* pt, fp g, fp bb, fp pos) {
  int bp0 = blockIdx.x * 16;
  int tid = threadIdx.x, wave = tid >> 6, lane = tid & 63;
  for (int i = 0; i < 4; i++) {
    int bp = bp0 + wave*4 + i;
    int p = bp % P_;
    float* row = pt + (size_t)bp*D_;
    float4 v0 = *(f4p)(row + lane*8);
    float4 v1 = *(f4p)(row + lane*8 + 4);
    float s = v0.x+v0.y+v0.z+v0.w + v1.x+v1.y+v1.z+v1.w;
    float q = f4dot(v0,v0) + f4dot(v1,v1);
    s = wred(s); q = wred(q);
    float mu = s / (float)D_;
    float var = q / (float)D_ - mu*mu;
    float rstd = 1.f / sqrtf(var + 1e-5f);
    for (int j = 0; j < 8; j++) {
      int c = lane*8 + j;
      float v = (j < 4) ? ((const float*)&v0)[j] : ((const float*)&v1)[j-4];
      row[c] = (v - mu)*rstd*g[c] + bb[c] + pos[p*D_ + c];
    }
  }
}

// ---- P2a: kvraw = pt @ kv_w.T + kv_b. grid (196 x 4), wave-coop. ----
__global__ __launch_bounds__(256) void k_kv_mm(const float* pt, fp kv_w, fp kv_b, float* kvraw) {
  int pg = blockIdx.x >> 2, rg = blockIdx.x & 3;
  int bp0 = pg * 16;
  int tid = threadIdx.x, wave = tid >> 6, lane = tid & 63;
  __shared__ float xin[16][516];
  for (int idx = tid; idx < 16*512; idx += 256) {
    int bb = idx >> 9, c = idx & 511;
    xin[bb][c] = pt[(size_t)(bp0 + bb)*D_ + c];
  }
  __syncthreads();
  for (int k = 0; k < 32; k++) {
    int r = rg*128 + wave*32 + k;
    const float* wr = kv_w + (size_t)r*512 + lane*4;
    float4 w0 = *(f4p)(wr), w1 = *(f4p)(wr + 256);
    float kb = kv_b[r];
    for (int half = 0; half < 2; half++) {
      float pp[8];
      for (int pi = 0; pi < 8; pi++) {
        const float* pb = &xin[half*8 + pi][lane*4];
        pp[pi] = f4dot(w0, *(f4p)(pb)) + f4dot(w1, *(f4p)(pb + 256));
      }
      for (int pi = 0; pi < 8; pi++) {
        float s = wred(pp[pi]);
        if (lane == 0) kvraw[(size_t)(bp0 + half*8 + pi)*D_ + r] = s + kb;
      }
    }
  }
}

// ---- P2b: LN in-place. grid 196. ----
__global__ __launch_bounds__(256) void k_kvln(float* kv, fp g, fp bb) {
  int bp0 = blockIdx.x * 16;
  int tid = threadIdx.x, wave = tid >> 6, lane = tid & 63;
  for (int i = 0; i < 4; i++) {
    int bp = bp0 + wave*4 + i;
    float* row = kv + (size_t)bp*D_;
    float4 v0 = *(f4p)(row + lane*8);
    float4 v1 = *(f4p)(row + lane*8 + 4);
    float s = v0.x+v0.y+v0.z+v0.w + v1.x+v1.y+v1.z+v1.w;
    float q = f4dot(v0,v0) + f4dot(v1,v1);
    s = wred(s); q = wred(q);
    float mu = s / (float)D_;
    float var = q / (float)D_ - mu*mu;
    float rstd = 1.f / sqrtf(var + 1e-5f);
    for (int j = 0; j < 8; j++) {
      int c = lane*8 + j;
      float v = (j < 4) ? ((const float*)&v0)[j] : ((const float*)&v1)[j-4];
      row[c] = (v - mu)*rstd*g[c] + bb[c];
    }
  }
}

// ---- P3: W_qc = (wq @ q_w) * 0.125. grid (32,32). once per call. ----
__global__ __launch_bounds__(256) void k_wqc(fp aw, fp q_w, float* W_qc) {
  int i0 = blockIdx.x * 16, s0 = blockIdx.y * 16;
  int tid = threadIdx.x, il = tid >> 4, sl = tid & 15;
  __shared__ float s_wq[16][129];
  __shared__ float s_qw[128][17];
  float acc = 0.f;
  for (int kc = 0; kc < 4; kc++) {
    int k0 = kc * 128;
    for (int idx = tid; idx < 2048; idx += 256) {
      int r = idx >> 7, c = idx & 127;
      s_wq[r][c] = aw[(size_t)(i0 + r)*512 + k0 + c];
    }
    for (int idx = tid; idx < 2048; idx += 256) {
      int r = idx >> 4, c = idx & 15;
      s_qw[r][c] = q_w[(size_t)(k0 + r)*512 + s0 + c];
    }
    __syncthreads();
    for (int kk = 0; kk < 128; kk++)
      acc += s_wq[il][kk] * s_qw[kk][sl];
    __syncthreads();
  }
  W_qc[(size_t)(i0 + il)*512 + s0 + sl] = 0.125f * acc;
}

// ---- P3b: bc = 0.125 * (wq @ q_b + bq). grid 2. ----
__global__ __launch_bounds__(256) void k_wqcb(fp aw, fp q_b, fp ab, float* bc) {
  int i = blockIdx.x * 256 + threadIdx.x;
  float acc = ab[i];
  for (int j = 0; j < 512; j++) acc += aw[(size_t)i*512 + j] * q_b[j];
  bc[i] = 0.125f * acc;
}

// ---- INIT ----
__global__ void k_init(fp start_state, fp start_trace, const int* oL, const int* oR,
                       float* act, float* trace, float* aa, float* ba, float* ao, float* bo) {
  int gid = blockIdx.x * 256 + threadIdx.x;
  if (gid < B_*N_*M_) {
    int bn = gid / M_, m = gid % M_;
    int n = bn % N_;
    trace[gid] = start_trace[n*M_ + m];
  }
  if (gid < B_*N_) act[gid] = start_state[gid & (N_-1)];
  if (gid < B_*SA_) { aa[gid] = 0.f; ba[gid] = 0.f; }
  if (gid < B_*SO_) {
    int s = gid & (SO_-1);
    ao[gid] = start_state[oL[s]] * start_state[oR[s]];
    bo[gid] = 1.0f;
  }
}

// ---- T1a: action sync -> sact_ws. grid 16. ----
__global__ __launch_bounds__(256) void k_sync1(const float* act, float* aa, float* ba,
                                               fp decay_a, const int* L, const int* R,
                                               float* sact_ws) {
  int b = blockIdx.x, tid = threadIdx.x;
  for (int cc = 0; cc < 2; cc++) {
    int s_ = tid + cc*256;
    float r = expf(-decay_a[s_]);
    float pair = act[b*N_ + L[s_]] * act[b*N_ + R[s_]];
    float a  = r*aa[b*SA_ + s_] + pair;
    float bt = r*ba[b*SA_ + s_] + 1.0f;
    aa[b*SA_ + s_] = a; ba[b*SA_ + s_] = bt;
    sact_ws[b*SA_ + s_] = a / sqrtf(bt);
  }
}

// ---- T1b: qh = sact @ W_qc.T + bc. grid (8,2): wave-coop, 8 batches LDS. ----
__global__ __launch_bounds__(256) void k_q(const float* sact_ws, const float* W_qc,
                                           const float* bc, float* qh) {
  int rb = blockIdx.x, bg = blockIdx.y;
  int tid = threadIdx.x, wave = tid >> 6, lane = tid & 63;
  __shared__ float s_x[8][516];
  for (int idx = tid; idx < 8*512; idx += 256) {
    int bb = idx >> 9, c = idx & 511;
    s_x[bb][c] = sact_ws[(bg*8 + bb)*SA_ + c];
  }
  __syncthreads();
  for (int k = 0; k < 16; k++) {
    int r = rb*64 + wave*16 + k;
    const float* wr = W_qc + (size_t)r*512 + lane*4;
    float4 w0 = *(f4p)(wr), w1 = *(f4p)(wr + 256);
    float pp[8];
    for (int bb = 0; bb < 8; bb++) {
      const float* pb = &s_x[bb][lane*4];
      pp[bb] = f4dot(w0, *(f4p)(pb)) + f4dot(w1, *(f4p)(pb + 256));
    }
    float bcr = bc[r];
    for (int bb = 0; bb < 8; bb++) {
      float s = wred(pp[bb]);
      if (lane == 0) qh[(bg*8 + bb)*D_ + r] = s + bcr;
    }
  }
}

// ---- T2: rank-space attention per (b,h). ----
__global__ __launch_bounds__(256) void k_attn(const float* qh, const float* kvb,
                                              fp aw, fp ab, float* zz) {
  int b = blockIdx.x, h = blockIdx.y;
  int tid = threadIdx.x, wave = tid >> 6, lane = tid & 63;
  __shared__ float qhh[64];
  __shared__ float qt[512];
  __shared__ float sc[256];
  __shared__ float red[256];
  __shared__ float zpart[4][512];
  if (tid < 64) qhh[tid] = qh[b*D_ + h*HD_ + tid];
  __syncthreads();
  float acc0 = 0.f, acc1 = 0.f;
  for (int e = 0; e < HD_; e++) {
    float q = qhh[e];
    const float* ar = aw + (size_t)(512 + h*HD_ + e)*D_;
    acc0 += q * ar[tid];
    acc1 += q * ar[tid + 256];
  }
  qt[tid] = acc0; qt[tid + 256] = acc1;
  float kb = 0.f;
  for (int e = 0; e < HD_; e++) kb += qhh[e] * ab[512 + h*HD_ + e];
  __syncthreads();
  for (int p = wave*49; p < wave*49 + 49; p++) {
    const float* kvp = kvb + ((size_t)(b*P_ + p))*D_;
    float s = f4dot(*(f4p)(kvp + lane*4),       *(f4p)(qt + lane*4))
            + f4dot(*(f4p)(kvp + 256 + lane*4), *(f4p)(qt + 256 + lane*4));
    s = wred(s);
    if (lane == 0) sc[p] = s + kb;
  }
  __syncthreads();
  float v = (tid < P_) ? sc[tid] : -1e30f;
  float m = breduce_max(v, red);
  float e = (tid < P_) ? expf(sc[tid] - m) : 0.f;
  if (tid < P_) sc[tid] = e;
  float ssum = breduce_sum(e, red);
  float inv = 1.f / ssum;
  float4 z0 = {0,0,0,0}, z1 = {0,0,0,0};
  for (int p = wave*49; p < wave*49 + 49; p++) {
    const float* kvp = kvb + ((size_t)(b*P_ + p))*D_ + lane*8;
    float w = sc[p];
    float4 a = *(f4p)(kvp), c = *(f4p)(kvp + 4);
    z0.x += w*a.x; z0.y += w*a.y; z0.z += w*a.z; z0.w += w*a.w;
    z1.x += w*c.x; z1.y += w*c.y; z1.z += w*c.z; z1.w += w*c.w;
  }
  *(float4*)(&zpart[wave][lane*8])     = z0;
  *(float4*)(&zpart[wave][lane*8 + 4]) = z1;
  __syncthreads();
  for (int cc = 0; cc < 2; cc++) {
    int c = tid + cc*256;
    zz[((size_t)(b*H_ + h))*D_ + c] =
      (zpart[0][c] + zpart[1][c] + zpart[2][c] + zpart[3][c]) * inv;
  }
}

// ---- T2b: av = zz_h @ wv.T + bv. grid (8,2): wave-coop. ----
__global__ __launch_bounds__(256) void k_av(const float* zz, fp aw, fp ab, float* av_ws) {
  int rb = blockIdx.x, bg = blockIdx.y;
  int tid = threadIdx.x, wave = tid >> 6, lane = tid & 63;
  int h = rb >> 1;                 // 64 rows per rb, 128 per head
  __shared__ float s_z[8][516];
  for (int idx = tid; idx < 8*512; idx += 256) {
    int bb = idx >> 9, c = idx & 511;
    s_z[bb][c] = zz[((size_t)((bg*8 + bb)*H_ + h))*D_ + c];
  }
  __syncthreads();
  for (int k = 0; k < 16; k++) {
    int r = rb*64 + wave*16 + k;
    const float* wr = aw + (size_t)(1024 + r)*512 + lane*4;
    float4 w0 = *(f4p)(wr), w1 = *(f4p)(wr + 256);
    float pp[8];
    for (int bb = 0; bb < 8; bb++) {
      const float* pb = &s_z[bb][lane*4];
      pp[bb] = f4dot(w0, *(f4p)(pb)) + f4dot(w1, *(f4p)(pb + 256));
    }
    float abr = ab[1024 + r];
    for (int bb = 0; bb < 8; bb++) {
      float s = wred(pp[bb]);
      if (lane == 0) av_ws[(bg*8 + bb)*D_ + r] = s + abr;
    }
  }
}

// ---- T2c: attn_o = av @ ow.T + ob. grid (8,2): wave-coop. ----
__global__ __launch_bounds__(256) void k_ao2(const float* av_ws, fp ow, fp ob, float* attn_o) {
  int rb = blockIdx.x, bg = blockIdx.y;
  int tid = threadIdx.x, wave = tid >> 6, lane = tid & 63;
  __shared__ float s_a[8][516];
  for (int idx = tid; idx < 8*512; idx += 256) {
    int bb = idx >> 9, c = idx & 511;
    s_a[bb][c] = av_ws[(bg*8 + bb)*D_ + c];
  }
  __syncthreads();
  for (int k = 0; k < 16; k++) {
    int r = rb*64 + wave*16 + k;
    const float* wr = ow + (size_t)r*512 + lane*4;
    float4 w0 = *(f4p)(wr), w1 = *(f4p)(wr + 256);
    float pp[8];
    for (int bb = 0; bb < 8; bb++) {
      const float* pb = &s_a[bb][lane*4];
      pp[bb] = f4dot(w0, *(f4p)(pb)) + f4dot(w1, *(f4p)(pb + 256));
    }
    float obr = ob[r];
    for (int bb = 0; bb < 8; bb++) {
      float s = wred(pp[bb]);
      if (lane == 0) attn_o[(bg*8 + bb)*D_ + r] = s + obr;
    }
  }
}

// ---- T3: y = pre @ syn_w.T + syn_b. grid (64,2): wave-coop, reg-cached weights. ----
__global__ __launch_bounds__(256) void k_syn(const float* attn_o, const float* act,
                                             fp syn_w, fp syn_b, float* y) {
  int rb = blockIdx.x;              // 64 row-blocks of 64 rows
  int bg = blockIdx.y;              // 2 batch-groups of 8
  int tid = threadIdx.x, wave = tid >> 6, lane = tid & 63;
  __shared__ float pre8[8][2560];
  for (int bb = 0; bb < 8; bb++) {
    int b = bg*8 + bb;
    for (int i = tid; i < 2560; i += 256)
      pre8[bb][i] = (i < 512) ? attn_o[b*D_ + i] : act[b*N_ + (i - 512)];
  }
  __syncthreads();
  for (int k = 0; k < 16; k++) {
    int r = rb*64 + wave*16 + k;
    const float* wr = syn_w + (size_t)r*2560 + lane*4;
    float4 wreg[10];
    for (int j = 0; j < 10; j++) wreg[j] = *(f4p)(wr + j*256);
    float pp[8] = {0,0,0,0,0,0,0,0};
    for (int j = 0; j < 10; j++) {
      int idx = lane*4 + j*256;
      for (int bb = 0; bb < 8; bb++)
        pp[bb] += f4dot(wreg[j], *(f4p)(&pre8[bb][idx]));
    }
    float sb = syn_b[r];
    for (int bb = 0; bb < 8; bb++) {
      float s = wred(pp[bb]);
      if (lane == 0) y[(size_t)(bg*8 + bb)*4096 + r] = s + sb;
    }
  }
}

// ---- T4: GLU + LN -> state. grid 16. ----
__global__ __launch_bounds__(256) void k_state(const float* y, fp g, fp bvec, float* state) {
  int b = blockIdx.x, tid = threadIdx.x;
  __shared__ float st[2048];
  __shared__ float red[256];
  float ls = 0.f, lq = 0.f;
  for (int ii = 0; ii < 8; ii++) {
    int c = ii*256 + tid;
    float a  = y[(size_t)b*4096 + c];
    float gg = y[(size_t)b*4096 + 2048 + c];
    float v = a * sigmf(gg);
    st[c] = v; ls += v; lq += v*v;
  }
  float S = breduce_sum(ls, red);
  float Q = breduce_sum(lq, red);
  float mu = S / (float)N_;
  float var = Q / (float)N_ - mu*mu;
  float rstd = 1.f / sqrtf(var + 1e-5f);
  for (int ii = 0; ii < 8; ii++) {
    int c = ii*256 + tid;
    state[b*N_ + c] = (st[c] - mu)*rstd*g[c] + bvec[c];
  }
}

// ---- T5: NLM per neuron; trace shift fused. grid 2048. ----
__global__ __launch_bounds__(256) void k_nlm(float* trace, const float* state,
                                             fp fc1_w, fp fc1_b, fp fc2_w, fp fc2_b,
                                             fp nlmT, float* act) {
  int n = blockIdx.x, tid = threadIdx.x;
  __shared__ float tr[B_][M_];
  __shared__ float uu[256][17];
  __shared__ float h1[128][17];
  __shared__ float vout[B_][2];
  for (int i = tid; i < B_*M_; i += 256) {
    int b = i / M_, m = i % M_;
    tr[b][m] = (m < M_-1) ? trace[((size_t)(b*N_ + n))*M_ + m + 1] : state[b*N_ + n];
  }
  __syncthreads();
  for (int i = tid; i < B_*M_; i += 256) {
    int b = i / M_, m = i % M_;
    trace[((size_t)(b*N_ + n))*M_ + m] = tr[b][m];
  }
  float w25[M_];
  for (int m = 0; m < M_; m++) w25[m] = fc1_w[((size_t)n*M_ + m)*256 + tid];
  float bias = fc1_b[n*256 + tid];
  for (int b = 0; b < B_; b++) {
    float u = bias;
    for (int m = 0; m < M_; m++) u += tr[b][m]*w25[m];
    uu[tid][b] = u;
  }
  __syncthreads();
  if (tid < 128) {
    for (int b = 0; b < B_; b++)
      h1[tid][b] = uu[tid][b] * sigmf(uu[tid + 128][b]);
  }
  __syncthreads();
  if (tid < 32) {
    int b = tid >> 1, o = tid & 1;
    float acc = fc2_b[n*2 + o];
    for (int hh = 0; hh < 128; hh++) acc += h1[hh][b] * fc2_w[((size_t)n*128 + hh)*2 + o];
    vout[b][o] = acc;
  }
  __syncthreads();
  if (tid < B_) {
    act[tid*N_ + n] = vout[tid][0] * sigmf(vout[tid][1]) / nlmT[0];
  }
}

// ---- T6a: out sync -> sout_ws. grid 16. ----
__global__ __launch_bounds__(256) void k_osync(const float* act, float* ao, float* bo,
                                               fp decay_o, const int* L, const int* R,
                                               float* sout_ws) {
  int b = blockIdx.x, tid = threadIdx.x;
  for (int cc = 0; cc < 4; cc++) {
    int s_ = tid + cc*256;
    float r = expf(-decay_o[s_]);
    float pair = act[b*N_ + L[s_]] * act[b*N_ + R[s_]];
    float a  = r*ao[b*SO_ + s_] + pair;
    float bt = r*bo[b*SO_ + s_] + 1.f;
    ao[b*SO_ + s_] = a; bo[b*SO_ + s_] = bt;
    sout_ws[b*SO_ + s_] = a / sqrtf(bt);
  }
}

// ---- T6b: preds direct to d_out. grid (25,2): wave-coop, 40 rows x 8 batches. ----
__global__ __launch_bounds__(256) void k_out(const float* sout_ws, fp out_w, fp out_b,
                                             float* out, int t) {
  int rb = blockIdx.x, bg = blockIdx.y;
  int tid = threadIdx.x, wave = tid >> 6, lane = tid & 63;
  __shared__ float s_sout[8][1024];
  for (int idx = tid; idx < 8*1024; idx += 256) {
    int bb = idx >> 10, c = idx & 1023;
    s_sout[bb][c] = sout_ws[(bg*8 + bb)*SO_ + c];
  }
  __syncthreads();
  for (int k = 0; k < 10; k++) {
    int r = rb*40 + wave*10 + k;
    const float* wr = out_w + (size_t)r*1024 + lane*4;
    float4 w0 = *(f4p)(wr),       w1 = *(f4p)(wr + 256),
           w2 = *(f4p)(wr + 512), w3 = *(f4p)(wr + 768);
    float pp[8];
    for (int bb = 0; bb < 8; bb++) {
      const float* pb = &s_sout[bb][lane*4];
      pp[bb] = f4dot(w0, *(f4p)(pb))       + f4dot(w1, *(f4p)(pb + 256))
             + f4dot(w2, *(f4p)(pb + 512)) + f4dot(w3, *(f4p)(pb + 768));
    }
    float obr = out_b[r];
    for (int bb = 0; bb < 8; bb++) {
      float s = wred(pp[bb]);
      if (lane == 0) out[((size_t)((bg*8 + bb)*O_ + r))*T_ + t] = s + obr;
    }
  }
}

// ---- T7: entropy. grid (16,16). ----
__global__ __launch_bounds__(256) void k_final(float* out) {
  int b = blockIdx.x, t = blockIdx.y, tid = threadIdx.x;
  __shared__ float red[256];
  float lm = -1e30f;
  for (int o = tid; o < O_; o += 256) lm = fmaxf(lm, out[((size_t)(b*O_ + o))*T_ + t]);
  float Mx = breduce_max(lm, red);
  float le = 0.f;
  for (int o = tid; o < O_; o += 256) le += expf(out[((size_t)(b*O_ + o))*T_ + t] - Mx);
  float S = breduce_sum(le, red);
  float lt = 0.f;
  for (int o = tid; o < O_; o += 256) {
    float pr = expf(out[((size_t)(b*O_ + o))*T_ + t] - Mx) / S;
    lt += pr * logf(pr + 1e-10f);
  }
  float E = breduce_sum(lt, red);
  if (tid == 0)
    out[(size_t)B_*O_*T_ + b*T_ + t] = -E / logf((float)O_);
}

extern "C" void kernel_launch(void* const* d_in, const int* in_sizes, int n_in,
                              void* d_out, int out_size, void* d_ws, size_t ws_size,
                              hipStream_t stream) {
  (void)in_sizes; (void)n_in; (void)out_size; (void)ws_size;
  fp x          = (fp)d_in[0];
  fp conv_w     = (fp)d_in[1];
  fp conv_b     = (fp)d_in[2];
  fp patch_ln_g = (fp)d_in[3];
  fp patch_ln_b = (fp)d_in[4];
  fp pos        = (fp)d_in[5];
  fp kv_w       = (fp)d_in[6];
  fp kv_b       = (fp)d_in[7];
  fp kv_ln_g    = (fp)d_in[8];
  fp kv_ln_b    = (fp)d_in[9];
  fp q_w        = (fp)d_in[10];
  fp q_b        = (fp)d_in[11];
  fp attn_in_w  = (fp)d_in[12];
  fp attn_in_b  = (fp)d_in[13];
  fp attn_out_w = (fp)d_in[14];
  fp attn_out_b = (fp)d_in[15];
  fp syn_w      = (fp)d_in[16];
  fp syn_b      = (fp)d_in[17];
  fp syn_ln_g   = (fp)d_in[18];
  fp syn_ln_b   = (fp)d_in[19];
  fp fc1_w      = (fp)d_in[20];
  fp fc1_b      = (fp)d_in[21];
  fp fc2_w      = (fp)d_in[22];
  fp fc2_b      = (fp)d_in[23];
  fp nlm_T      = (fp)d_in[24];
  fp start_state= (fp)d_in[25];
  fp start_trace= (fp)d_in[26];
  fp decay_a    = (fp)d_in[27];
  fp decay_o    = (fp)d_in[28];
  fp out_w      = (fp)d_in[29];
  fp out_b      = (fp)d_in[30];
  const int* act_left  = (const int*)d_in[31];
  const int* act_right = (const int*)d_in[32];
  const int* out_left  = (const int*)d_in[33];
  const int* out_right = (const int*)d_in[34];

  // ws: region X [0, 1605632) holds pt during precompute, then per-tick state.
  float* ws = (float*)d_ws;
  float* pt     = ws;                          // precompute only
  float* act    = ws + 0;                      // 32768
  float* trace  = ws + 32768;                  // 819200
  float* aa     = ws + 851968;                 // 8192
  float* ba     = ws + 860160;                 // 8192
  float* ao     = ws + 868352;                 // 16384
  float* bo     = ws + 884736;                 // 16384
  float* qh     = ws + 901120;                 // 8192
  float* attn_o = ws + 909312;                 // 8192
  float* ysyn   = ws + 917504;                 // 65536
  float* state  = ws + 983040;                 // 32768
  float* zz     = ws + 1015808;                // 65536
  float* sact_ws= ws + 1081344;                // 8192
  float* av_ws  = ws + 1089536;                // 8192
  float* sout_ws= ws + 1097728;                // 16384
  float* W_qc   = ws + 1114112;                // 262144
  float* bc     = ws + 1376256;                // 512 -> 1376768 < 1605632
  float* kvb    = ws + 1605632;                // 1605632

  k_patch_mm<<<dim3(196*4), dim3(256), 0, stream>>>(x, conv_w, conv_b, pt);
  k_pln<<<dim3(196), dim3(256), 0, stream>>>(pt, patch_ln_g, patch_ln_b, pos);
  k_kv_mm<<<dim3(196*4), dim3(256), 0, stream>>>(pt, kv_w, kv_b, kvb);
  k_kvln<<<dim3(196), dim3(256), 0, stream>>>(kvb, kv_ln_g, kv_ln_b);
  // pt dead; safe to write W_qc / state region now.
  k_wqc<<<dim3(32, 32), dim3(256), 0, stream>>>(attn_in_w, q_w, W_qc);
  k_wqcb<<<dim3(2), dim3(256), 0, stream>>>(attn_in_w, q_b, attn_in_b, bc);
  k_init<<<dim3((B_*N_*M_ + 255)/256), dim3(256), 0, stream>>>(start_state, start_trace,
        out_left, out_right, act, trace, aa, ba, ao, bo);

  for (int t = 0; t < T_; t++) {
    k_sync1<<<dim3(B_), dim3(256), 0, stream>>>(act, aa, ba, decay_a, act_left, act_right, sact_ws);
    k_q<<<dim3(8, 2), dim3(256), 0, stream>>>(sact_ws, W_qc, bc, qh);
    k_attn<<<dim3(B_, H_), dim3(256), 0, stream>>>(qh, kvb, attn_in_w, attn_in_b, zz);
    k_av<<<dim3(8, 2), dim3(256), 0, stream>>>(zz, attn_in_w, attn_in_b, av_ws);
    k_ao2<<<dim3(8, 2), dim3(256), 0, stream>>>(av_ws, attn_out_w, attn_out_b, attn_o);
    k_syn<<<dim3(64, 2), dim3(256), 0, stream>>>(attn_o, act, syn_w, syn_b, ysyn);
    k_state<<<dim3(B_), dim3(256), 0, stream>>>(ysyn, syn_ln_g, syn_ln_b, state);
    k_nlm<<<dim3(N_), dim3(256), 0, stream>>>(trace, state, fc1_w, fc1_b, fc2_w, fc2_b,
                                              nlm_T, act);
    k_osync<<<dim3(B_), dim3(256), 0, stream>>>(act, ao, bo, decay_o, out_left, out_right, sout_ws);
    k_out<<<dim3(25, 2), dim3(256), 0, stream>>>(sout_ws, out_w, out_b, (float*)d_out, t);
  }
  k_final<<<dim3(B_, T_), dim3(256), 0, stream>>>((float*)d_out);
}

// Round 9
// 4614.231 us; speedup vs baseline: 3.1444x; 1.0590x over previous
//
#include <hip/hip_runtime.h>
#include <hip/hip_bf16.h>
#include <math.h>

// SimplifiedCTM on MI355X — round 9: fuse per-tick chain 10 -> 7 dispatches.
// - k_syncq = sync_action + q-GEMV (sync recomputed per block; rb==0 persists
//   into tick-parity double buffer).
// - k_attn computes av in-block (zz never leaves LDS).
// - k_outf = out-sync + preds GEMV (double-buffered ao/bo).
// - exp(-decay) hoisted to k_init.

#define DEV __device__ __forceinline__
typedef const float* fp;
typedef const float4* f4p;

#define B_   16
#define P_   196
#define D_   512
#define H_   8
#define HD_  64
#define N_   2048
#define M_   25
#define SA_  512
#define SO_  1024
#define O_   1000
#define T_   16

DEV float sigmf(float x){ return 1.0f / (1.0f + expf(-x)); }
DEV float wred(float v) { for (int m = 32; m; m >>= 1) v += __shfl_xor(v, m); return v; }
DEV float f4dot(float4 a, float4 b) { return a.x*b.x + a.y*b.y + a.z*b.z + a.w*b.w; }

DEV float breduce_sum(float v, float* red) {
  int t = threadIdx.x;
  red[t] = v; __syncthreads();
  for (int s = blockDim.x >> 1; s > 0; s >>= 1) {
    if (t < s) red[t] += red[t + s];
    __syncthreads();
  }
  float r = red[0]; __syncthreads();
  return r;
}
DEV float breduce_max(float v, float* red) {
  int t = threadIdx.x;
  red[t] = v; __syncthreads();
  for (int s = blockDim.x >> 1; s > 0; s >>= 1) {
    if (t < s) red[t] = fmaxf(red[t], red[t + s]);
    __syncthreads();
  }
  float r = red[0]; __syncthreads();
  return r;
}

// ---- P1a: conv-as-GEMM. grid (196 x 4). ----
__global__ __launch_bounds__(256) void k_patch_mm(fp x, fp conv_w, fp conv_b, float* ptraw) {
  int pg = blockIdx.x >> 2, rg = blockIdx.x & 3;
  int bp0 = pg * 16;
  int tid = threadIdx.x, wave = tid >> 6, lane = tid & 63;
  __shared__ float patch[16][772];
  for (int pi = 0; pi < 16; pi++) {
    int bp = bp0 + pi, b = bp / P_, p = bp % P_;
    int ph = p / 14, pw = p % 14;
    for (int j = tid; j < 768; j += 256) {
      int ci = j >> 8, r = j & 255, qi = r >> 4, qj = r & 15;
      patch[pi][j] = x[((size_t)(b*3 + ci)*224 + (ph*16 + qi))*224 + (pw*16 + qj)];
    }
  }
  __syncthreads();
  for (int k = 0; k < 32; k++) {
    int r = rg*128 + wave*32 + k;
    const float* wr = conv_w + (size_t)r*768 + lane*4;
    float4 w0 = *(f4p)(wr), w1 = *(f4p)(wr + 256), w2 = *(f4p)(wr + 512);
    float cb = conv_b[r];
    for (int half = 0; half < 2; half++) {
      float pp[8];
      for (int pi = 0; pi < 8; pi++) {
        const float* pb = &patch[half*8 + pi][lane*4];
        pp[pi] = f4dot(w0, *(f4p)(pb)) + f4dot(w1, *(f4p)(pb + 256))
               + f4dot(w2, *(f4p)(pb + 512));
      }
      for (int pi = 0; pi < 8; pi++) {
        float s = wred(pp[pi]);
        if (lane == 0) ptraw[(size_t)(bp0 + half*8 + pi)*D_ + r] = s + cb;
      }
    }
  }
}

// ---- P1b: LN + pos (in-place). grid 196. ----
__global__ __launch_bounds__(256) void k_pln(float* pt, fp g, fp bb, fp pos) {
  int bp0 = blockIdx.x * 16;
  int tid = threadIdx.x, wave = tid >> 6, lane = tid & 63;
  for (int i = 0; i < 4; i++) {
    int bp = bp0 + wave*4 + i;
    int p = bp % P_;
    float* row = pt + (size_t)bp*D_;
    float4 v0 = *(f4p)(row + lane*8);
    float4 v1 = *(f4p)(row + lane*8 + 4);
    float s = v0.x+v0.y+v0.z+v0.w + v1.x+v1.y+v1.z+v1.w;
    float q = f4dot(v0,v0) + f4dot(v1,v1);
    s = wred(s); q = wred(q);
    float mu = s / (float)D_;
    float var = q / (float)D_ - mu*mu;
    float rstd = 1.f / sqrtf(var + 1e-5f);
    for (int j = 0; j < 8; j++) {
      int c = lane*8 + j;
      float v = (j < 4) ? ((const float*)&v0)[j] : ((const float*)&v1)[j-4];
      row[c] = (v - mu)*rstd*g[c] + bb[c] + pos[p*D_ + c];
    }
  }
}

// ---- P2a: kvraw = pt @ kv_w.T + kv_b. grid (196 x 4). ----
__global__ __launch_bounds__(256) void k_kv_mm(const float* pt, fp kv_w, fp kv_b, float* kvraw) {
  int pg = blockIdx.x >> 2, rg = blockIdx.x & 3;
  int bp0 = pg * 16;
  int tid = threadIdx.x, wave = tid >> 6, lane = tid & 63;
  __shared__ float xin[16][516];
  for (int idx = tid; idx < 16*512; idx += 256) {
    int bb = idx >> 9, c = idx & 511;
    xin[bb][c] = pt[(size_t)(bp0 + bb)*D_ + c];
  }
  __syncthreads();
  for (int k = 0; k < 32; k++) {
    int r = rg*128 + wave*32 + k;
    const float* wr = kv_w + (size_t)r*512 + lane*4;
    float4 w0 = *(f4p)(wr), w1 = *(f4p)(wr + 256);
    float kb = kv_b[r];
    for (int half = 0; half < 2; half++) {
      float pp[8];
      for (int pi = 0; pi < 8; pi++) {
        const float* pb = &xin[half*8 + pi][lane*4];
        pp[pi] = f4dot(w0, *(f4p)(pb)) + f4dot(w1, *(f4p)(pb + 256));
      }
      for (int pi = 0; pi < 8; pi++) {
        float s = wred(pp[pi]);
        if (lane == 0) kvraw[(size_t)(bp0 + half*8 + pi)*D_ + r] = s + kb;
      }
    }
  }
}

// ---- P2b: LN in-place. grid 196. ----
__global__ __launch_bounds__(256) void k_kvln(float* kv, fp g, fp bb) {
  int bp0 = blockIdx.x * 16;
  int tid = threadIdx.x, wave = tid >> 6, lane = tid & 63;
  for (int i = 0; i < 4; i++) {
    int bp = bp0 + wave*4 + i;
    float* row = kv + (size_t)bp*D_;
    float4 v0 = *(f4p)(row + lane*8);
    float4 v1 = *(f4p)(row + lane*8 + 4);
    float s = v0.x+v0.y+v0.z+v0.w + v1.x+v1.y+v1.z+v1.w;
    float q = f4dot(v0,v0) + f4dot(v1,v1);
    s = wred(s); q = wred(q);
    float mu = s / (float)D_;
    float var = q / (float)D_ - mu*mu;
    float rstd = 1.f / sqrtf(var + 1e-5f);
    for (int j = 0; j < 8; j++) {
      int c = lane*8 + j;
      float v = (j < 4) ? ((const float*)&v0)[j] : ((const float*)&v1)[j-4];
      row[c] = (v - mu)*rstd*g[c] + bb[c];
    }
  }
}

// ---- P3: W_qc = (wq @ q_w) * 0.125. grid (32,32). ----
__global__ __launch_bounds__(256) void k_wqc(fp aw, fp q_w, float* W_qc) {
  int i0 = blockIdx.x * 16, s0 = blockIdx.y * 16;
  int tid = threadIdx.x, il = tid >> 4, sl = tid & 15;
  __shared__ float s_wq[16][129];
  __shared__ float s_qw[128][17];
  float acc = 0.f;
  for (int kc = 0; kc < 4; kc++) {
    int k0 = kc * 128;
    for (int idx = tid; idx < 2048; idx += 256) {
      int r = idx >> 7, c = idx & 127;
      s_wq[r][c] = aw[(size_t)(i0 + r)*512 + k0 + c];
    }
    for (int idx = tid; idx < 2048; idx += 256) {
      int r = idx >> 4, c = idx & 15;
      s_qw[r][c] = q_w[(size_t)(k0 + r)*512 + s0 + c];
    }
    __syncthreads();
    for (int kk = 0; kk < 128; kk++)
      acc += s_wq[il][kk] * s_qw[kk][sl];
    __syncthreads();
  }
  W_qc[(size_t)(i0 + il)*512 + s0 + sl] = 0.125f * acc;
}

// ---- P3b: bc = 0.125 * (wq @ q_b + bq). grid 2. ----
__global__ __launch_bounds__(256) void k_wqcb(fp aw, fp q_b, fp ab, float* bc) {
  int i = blockIdx.x * 256 + threadIdx.x;
  float acc = ab[i];
  for (int j = 0; j < 512; j++) acc += aw[(size_t)i*512 + j] * q_b[j];
  bc[i] = 0.125f * acc;
}

// ---- INIT: state buffers (A-parity) + decay exp tables. ----
__global__ void k_init(fp start_state, fp start_trace, const int* oL, const int* oR,
                       fp decay_a, fp decay_o,
                       float* act, float* trace, float* aaA, float* baA,
                       float* aoA, float* boA, float* r_a, float* r_o) {
  int gid = blockIdx.x * 256 + threadIdx.x;
  if (gid < B_*N_*M_) {
    int bn = gid / M_, m = gid % M_;
    int n = bn % N_;
    trace[gid] = start_trace[n*M_ + m];
  }
  if (gid < B_*N_) act[gid] = start_state[gid & (N_-1)];
  if (gid < B_*SA_) { aaA[gid] = 0.f; baA[gid] = 0.f; }
  if (gid < B_*SO_) {
    int s = gid & (SO_-1);
    aoA[gid] = start_state[oL[s]] * start_state[oR[s]];
    boA[gid] = 1.0f;
  }
  if (gid < SA_) r_a[gid] = expf(-decay_a[gid]);
  if (gid < SO_) r_o[gid] = expf(-decay_o[gid]);
}

// ---- T1: fused action-sync + q GEMV. grid (8,2). ----
__global__ __launch_bounds__(256) void k_syncq(const float* act, const float* aaR, const float* baR,
                                               float* aaW, float* baW, const float* r_a,
                                               const int* L, const int* R,
                                               const float* W_qc, const float* bc, float* qh) {
  int rb = blockIdx.x, bg = blockIdx.y;
  int tid = threadIdx.x, wave = tid >> 6, lane = tid & 63;
  __shared__ float s_x[8][516];
  for (int i = 0; i < 16; i++) {
    int idx = tid + i*256;
    int bb = idx >> 9, s = idx & 511;
    int b = bg*8 + bb;
    float r = r_a[s];
    float pair = act[b*N_ + L[s]] * act[b*N_ + R[s]];
    float a  = r*aaR[b*SA_ + s] + pair;
    float bt = r*baR[b*SA_ + s] + 1.0f;
    if (rb == 0) { aaW[b*SA_ + s] = a; baW[b*SA_ + s] = bt; }
    s_x[bb][s] = a / sqrtf(bt);
  }
  __syncthreads();
  for (int k = 0; k < 16; k++) {
    int r = rb*64 + wave*16 + k;
    const float* wr = W_qc + (size_t)r*512 + lane*4;
    float4 w0 = *(f4p)(wr), w1 = *(f4p)(wr + 256);
    float pp[8];
    for (int bb = 0; bb < 8; bb++) {
      const float* pb = &s_x[bb][lane*4];
      pp[bb] = f4dot(w0, *(f4p)(pb)) + f4dot(w1, *(f4p)(pb + 256));
    }
    float bcr = bc[r];
    for (int bb = 0; bb < 8; bb++) {
      float s = wred(pp[bb]);
      if (lane == 0) qh[(bg*8 + bb)*D_ + r] = s + bcr;
    }
  }
}

// ---- T2: rank-space attention + in-block av. grid (16,8). ----
__global__ __launch_bounds__(256) void k_attn(const float* qh, const float* kvb,
                                              fp aw, fp ab, float* av_ws) {
  int b = blockIdx.x, h = blockIdx.y;
  int tid = threadIdx.x, wave = tid >> 6, lane = tid & 63;
  __shared__ float qhh[64];
  __shared__ float qt[512];
  __shared__ float sc[256];
  __shared__ float red[256];
  __shared__ float zpart[4][512];
  __shared__ float zzL[512];
  if (tid < 64) qhh[tid] = qh[b*D_ + h*HD_ + tid];
  __syncthreads();
  float acc0 = 0.f, acc1 = 0.f;
  for (int e = 0; e < HD_; e++) {
    float q = qhh[e];
    const float* ar = aw + (size_t)(512 + h*HD_ + e)*D_;
    acc0 += q * ar[tid];
    acc1 += q * ar[tid + 256];
  }
  qt[tid] = acc0; qt[tid + 256] = acc1;
  float kb = 0.f;
  for (int e = 0; e < HD_; e++) kb += qhh[e] * ab[512 + h*HD_ + e];
  __syncthreads();
  for (int p = wave*49; p < wave*49 + 49; p++) {
    const float* kvp = kvb + ((size_t)(b*P_ + p))*D_;
    float s = f4dot(*(f4p)(kvp + lane*4),       *(f4p)(qt + lane*4))
            + f4dot(*(f4p)(kvp + 256 + lane*4), *(f4p)(qt + 256 + lane*4));
    s = wred(s);
    if (lane == 0) sc[p] = s + kb;
  }
  __syncthreads();
  float v = (tid < P_) ? sc[tid] : -1e30f;
  float m = breduce_max(v, red);
  float e = (tid < P_) ? expf(sc[tid] - m) : 0.f;
  if (tid < P_) sc[tid] = e;
  float ssum = breduce_sum(e, red);
  float inv = 1.f / ssum;
  float4 z0 = {0,0,0,0}, z1 = {0,0,0,0};
  for (int p = wave*49; p < wave*49 + 49; p++) {
    const float* kvp = kvb + ((size_t)(b*P_ + p))*D_ + lane*8;
    float w = sc[p];
    float4 a = *(f4p)(kvp), c = *(f4p)(kvp + 4);
    z0.x += w*a.x; z0.y += w*a.y; z0.z += w*a.z; z0.w += w*a.w;
    z1.x += w*c.x; z1.y += w*c.y; z1.z += w*c.z; z1.w += w*c.w;
  }
  *(float4*)(&zpart[wave][lane*8])     = z0;
  *(float4*)(&zpart[wave][lane*8 + 4]) = z1;
  __syncthreads();
  for (int cc = 0; cc < 2; cc++) {
    int c = tid + cc*256;
    zzL[c] = (zpart[0][c] + zpart[1][c] + zpart[2][c] + zpart[3][c]) * inv;
  }
  __syncthreads();
  // av for this head: 64 rows, 16/wave, K=512 against zzL.
  for (int k = 0; k < 16; k++) {
    int e2 = wave*16 + k;
    int r = 1024 + h*HD_ + e2;
    const float* wr = aw + (size_t)r*512 + lane*4;
    float s = f4dot(*(f4p)(wr),       *(f4p)(&zzL[lane*4]))
            + f4dot(*(f4p)(wr + 256), *(f4p)(&zzL[lane*4 + 256]));
    s = wred(s);
    if (lane == 0) av_ws[b*D_ + h*HD_ + e2] = s + ab[r];
  }
}

// ---- T2c: attn_o = av @ ow.T + ob. grid (8,2). ----
__global__ __launch_bounds__(256) void k_ao2(const float* av_ws, fp ow, fp ob, float* attn_o) {
  int rb = blockIdx.x, bg = blockIdx.y;
  int tid = threadIdx.x, wave = tid >> 6, lane = tid & 63;
  __shared__ float s_a[8][516];
  for (int idx = tid; idx < 8*512; idx += 256) {
    int bb = idx >> 9, c = idx & 511;
    s_a[bb][c] = av_ws[(bg*8 + bb)*D_ + c];
  }
  __syncthreads();
  for (int k = 0; k < 16; k++) {
    int r = rb*64 + wave*16 + k;
    const float* wr = ow + (size_t)r*512 + lane*4;
    float4 w0 = *(f4p)(wr), w1 = *(f4p)(wr + 256);
    float pp[8];
    for (int bb = 0; bb < 8; bb++) {
      const float* pb = &s_a[bb][lane*4];
      pp[bb] = f4dot(w0, *(f4p)(pb)) + f4dot(w1, *(f4p)(pb + 256));
    }
    float obr = ob[r];
    for (int bb = 0; bb < 8; bb++) {
      float s = wred(pp[bb]);
      if (lane == 0) attn_o[(bg*8 + bb)*D_ + r] = s + obr;
    }
  }
}

// ---- T3: y = pre @ syn_w.T + syn_b. grid (64,2). ----
__global__ __launch_bounds__(256) void k_syn(const float* attn_o, const float* act,
                                             fp syn_w, fp syn_b, float* y) {
  int rb = blockIdx.x, bg = blockIdx.y;
  int tid = threadIdx.x, wave = tid >> 6, lane = tid & 63;
  __shared__ float pre8[8][2560];
  for (int bb = 0; bb < 8; bb++) {
    int b = bg*8 + bb;
    for (int i = tid; i < 2560; i += 256)
      pre8[bb][i] = (i < 512) ? attn_o[b*D_ + i] : act[b*N_ + (i - 512)];
  }
  __syncthreads();
  for (int k = 0; k < 16; k++) {
    int r = rb*64 + wave*16 + k;
    const float* wr = syn_w + (size_t)r*2560 + lane*4;
    float4 wreg[10];
    for (int j = 0; j < 10; j++) wreg[j] = *(f4p)(wr + j*256);
    float pp[8] = {0,0,0,0,0,0,0,0};
    for (int j = 0; j < 10; j++) {
      int idx = lane*4 + j*256;
      for (int bb = 0; bb < 8; bb++)
        pp[bb] += f4dot(wreg[j], *(f4p)(&pre8[bb][idx]));
    }
    float sb = syn_b[r];
    for (int bb = 0; bb < 8; bb++) {
      float s = wred(pp[bb]);
      if (lane == 0) y[(size_t)(bg*8 + bb)*4096 + r] = s + sb;
    }
  }
}

// ---- T4: GLU + LN -> state. grid 16. ----
__global__ __launch_bounds__(256) void k_state(const float* y, fp g, fp bvec, float* state) {
  int b = blockIdx.x, tid = threadIdx.x;
  __shared__ float st[2048];
  __shared__ float red[256];
  float ls = 0.f, lq = 0.f;
  for (int ii = 0; ii < 8; ii++) {
    int c = ii*256 + tid;
    float a  = y[(size_t)b*4096 + c];
    float gg = y[(size_t)b*4096 + 2048 + c];
    float v = a * sigmf(gg);
    st[c] = v; ls += v; lq += v*v;
  }
  float S = breduce_sum(ls, red);
  float Q = breduce_sum(lq, red);
  float mu = S / (float)N_;
  float var = Q / (float)N_ - mu*mu;
  float rstd = 1.f / sqrtf(var + 1e-5f);
  for (int ii = 0; ii < 8; ii++) {
    int c = ii*256 + tid;
    state[b*N_ + c] = (st[c] - mu)*rstd*g[c] + bvec[c];
  }
}

// ---- T5: NLM per neuron; trace shift fused. grid 2048. ----
__global__ __launch_bounds__(256) void k_nlm(float* trace, const float* state,
                                             fp fc1_w, fp fc1_b, fp fc2_w, fp fc2_b,
                                             fp nlmT, float* act) {
  int n = blockIdx.x, tid = threadIdx.x;
  __shared__ float tr[B_][M_];
  __shared__ float uu[256][17];
  __shared__ float h1[128][17];
  __shared__ float vout[B_][2];
  for (int i = tid; i < B_*M_; i += 256) {
    int b = i / M_, m = i % M_;
    tr[b][m] = (m < M_-1) ? trace[((size_t)(b*N_ + n))*M_ + m + 1] : state[b*N_ + n];
  }
  __syncthreads();
  for (int i = tid; i < B_*M_; i += 256) {
    int b = i / M_, m = i % M_;
    trace[((size_t)(b*N_ + n))*M_ + m] = tr[b][m];
  }
  float w25[M_];
  for (int m = 0; m < M_; m++) w25[m] = fc1_w[((size_t)n*M_ + m)*256 + tid];
  float bias = fc1_b[n*256 + tid];
  for (int b = 0; b < B_; b++) {
    float u = bias;
    for (int m = 0; m < M_; m++) u += tr[b][m]*w25[m];
    uu[tid][b] = u;
  }
  __syncthreads();
  if (tid < 128) {
    for (int b = 0; b < B_; b++)
      h1[tid][b] = uu[tid][b] * sigmf(uu[tid + 128][b]);
  }
  __syncthreads();
  if (tid < 32) {
    int b = tid >> 1, o = tid & 1;
    float acc = fc2_b[n*2 + o];
    for (int hh = 0; hh < 128; hh++) acc += h1[hh][b] * fc2_w[((size_t)n*128 + hh)*2 + o];
    vout[b][o] = acc;
  }
  __syncthreads();
  if (tid < B_) {
    act[tid*N_ + n] = vout[tid][0] * sigmf(vout[tid][1]) / nlmT[0];
  }
}

// ---- T6: fused out-sync + preds GEMV. grid (25,2). ----
__global__ __launch_bounds__(256) void k_outf(const float* act, const float* aoR, const float* boR,
                                              float* aoW, float* boW, const float* r_o,
                                              const int* L, const int* R,
                                              fp out_w, fp out_b, float* out, int t) {
  int rb = blockIdx.x, bg = blockIdx.y;
  int tid = threadIdx.x, wave = tid >> 6, lane = tid & 63;
  __shared__ float s_sout[8][1024];
  for (int i = 0; i < 32; i++) {
    int idx = tid + i*256;
    int bb = idx >> 10, s = idx & 1023;
    int b = bg*8 + bb;
    float r = r_o[s];
    float pair = act[b*N_ + L[s]] * act[b*N_ + R[s]];
    float a  = r*aoR[b*SO_ + s] + pair;
    float bt = r*boR[b*SO_ + s] + 1.f;
    if (rb == 0) { aoW[b*SO_ + s] = a; boW[b*SO_ + s] = bt; }
    s_sout[bb][s] = a / sqrtf(bt);
  }
  __syncthreads();
  for (int k = 0; k < 10; k++) {
    int r = rb*40 + wave*10 + k;
    const float* wr = out_w + (size_t)r*1024 + lane*4;
    float4 w0 = *(f4p)(wr),       w1 = *(f4p)(wr + 256),
           w2 = *(f4p)(wr + 512), w3 = *(f4p)(wr + 768);
    float pp[8];
    for (int bb = 0; bb < 8; bb++) {
      const float* pb = &s_sout[bb][lane*4];
      pp[bb] = f4dot(w0, *(f4p)(pb))       + f4dot(w1, *(f4p)(pb + 256))
             + f4dot(w2, *(f4p)(pb + 512)) + f4dot(w3, *(f4p)(pb + 768));
    }
    float obr = out_b[r];
    for (int bb = 0; bb < 8; bb++) {
      float s = wred(pp[bb]);
      if (lane == 0) out[((size_t)((bg*8 + bb)*O_ + r))*T_ + t] = s + obr;
    }
  }
}

// ---- T7: entropy. grid (16,16). ----
__global__ __launch_bounds__(256) void k_final(float* out) {
  int b = blockIdx.x, t = blockIdx.y, tid = threadIdx.x;
  __shared__ float red[256];
  float lm = -1e30f;
  for (int o = tid; o < O_; o += 256) lm = fmaxf(lm, out[((size_t)(b*O_ + o))*T_ + t]);
  float Mx = breduce_max(lm, red);
  float le = 0.f;
  for (int o = tid; o < O_; o += 256) le += expf(out[((size_t)(b*O_ + o))*T_ + t] - Mx);
  float S = breduce_sum(le, red);
  float lt = 0.f;
  for (int o = tid; o < O_; o += 256) {
    float pr = expf(out[((size_t)(b*O_ + o))*T_ + t] - Mx) / S;
    lt += pr * logf(pr + 1e-10f);
  }
  float E = breduce_sum(lt, red);
  if (tid == 0)
    out[(size_t)B_*O_*T_ + b*T_ + t] = -E / logf((float)O_);
}

extern "C" void kernel_launch(void* const* d_in, const int* in_sizes, int n_in,
                              void* d_out, int out_size, void* d_ws, size_t ws_size,
                              hipStream_t stream) {
  (void)in_sizes; (void)n_in; (void)out_size; (void)ws_size;
  fp x          = (fp)d_in[0];
  fp conv_w     = (fp)d_in[1];
  fp conv_b     = (fp)d_in[2];
  fp patch_ln_g = (fp)d_in[3];
  fp patch_ln_b = (fp)d_in[4];
  fp pos        = (fp)d_in[5];
  fp kv_w       = (fp)d_in[6];
  fp kv_b       = (fp)d_in[7];
  fp kv_ln_g    = (fp)d_in[8];
  fp kv_ln_b    = (fp)d_in[9];
  fp q_w        = (fp)d_in[10];
  fp q_b        = (fp)d_in[11];
  fp attn_in_w  = (fp)d_in[12];
  fp attn_in_b  = (fp)d_in[13];
  fp attn_out_w = (fp)d_in[14];
  fp attn_out_b = (fp)d_in[15];
  fp syn_w      = (fp)d_in[16];
  fp syn_b      = (fp)d_in[17];
  fp syn_ln_g   = (fp)d_in[18];
  fp syn_ln_b   = (fp)d_in[19];
  fp fc1_w      = (fp)d_in[20];
  fp fc1_b      = (fp)d_in[21];
  fp fc2_w      = (fp)d_in[22];
  fp fc2_b      = (fp)d_in[23];
  fp nlm_T      = (fp)d_in[24];
  fp start_state= (fp)d_in[25];
  fp start_trace= (fp)d_in[26];
  fp decay_a    = (fp)d_in[27];
  fp decay_o    = (fp)d_in[28];
  fp out_w      = (fp)d_in[29];
  fp out_b      = (fp)d_in[30];
  const int* act_left  = (const int*)d_in[31];
  const int* act_right = (const int*)d_in[32];
  const int* out_left  = (const int*)d_in[33];
  const int* out_right = (const int*)d_in[34];

  // Region X [0, 1605632) holds pt during precompute, then per-tick state.
  float* ws = (float*)d_ws;
  float* pt     = ws;                          // precompute only
  float* act    = ws + 0;                      // 32768
  float* trace  = ws + 32768;                  // 819200 -> 851968
  float* aaA    = ws + 851968;                 // 8192
  float* aaB    = ws + 860160;                 // 8192
  float* baA    = ws + 868352;                 // 8192
  float* baB    = ws + 876544;                 // 8192 -> 884736
  float* aoA    = ws + 884736;                 // 16384
  float* aoB    = ws + 901120;                 // 16384
  float* boA    = ws + 917504;                 // 16384
  float* boB    = ws + 933888;                 // 16384 -> 950272
  float* qh     = ws + 950272;                 // 8192
  float* attn_o = ws + 958464;                 // 8192
  float* ysyn   = ws + 966656;                 // 65536 -> 1032192
  float* state  = ws + 1032192;                // 32768
  float* av_ws  = ws + 1064960;                // 8192
  float* r_a    = ws + 1073152;                // 512
  float* r_o    = ws + 1073664;                // 1024 -> 1074688
  float* W_qc   = ws + 1074688;                // 262144 -> 1336832
  float* bc     = ws + 1336832;                // 512 -> 1337344 < 1605632
  float* kvb    = ws + 1605632;                // 1605632

  k_patch_mm<<<dim3(196*4), dim3(256), 0, stream>>>(x, conv_w, conv_b, pt);
  k_pln<<<dim3(196), dim3(256), 0, stream>>>(pt, patch_ln_g, patch_ln_b, pos);
  k_kv_mm<<<dim3(196*4), dim3(256), 0, stream>>>(pt, kv_w, kv_b, kvb);
  k_kvln<<<dim3(196), dim3(256), 0, stream>>>(kvb, kv_ln_g, kv_ln_b);
  // pt dead; safe to write W_qc / state region now.
  k_wqc<<<dim3(32, 32), dim3(256), 0, stream>>>(attn_in_w, q_w, W_qc);
  k_wqcb<<<dim3(2), dim3(256), 0, stream>>>(attn_in_w, q_b, attn_in_b, bc);
  k_init<<<dim3((B_*N_*M_ + 255)/256), dim3(256), 0, stream>>>(start_state, start_trace,
        out_left, out_right, decay_a, decay_o, act, trace, aaA, baA, aoA, boA, r_a, r_o);

  for (int t = 0; t < T_; t++) {
    float* aaR = (t & 1) ? aaB : aaA;  float* aaW = (t & 1) ? aaA : aaB;
    float* baR = (t & 1) ? baB : baA;  float* baW = (t & 1) ? baA : baB;
    float* aoR = (t & 1) ? aoB : aoA;  float* aoW = (t & 1) ? aoA : aoB;
    float* boR = (t & 1) ? boB : boA;  float* boW = (t & 1) ? boA : boB;
    k_syncq<<<dim3(8, 2), dim3(256), 0, stream>>>(act, aaR, baR, aaW, baW, r_a,
                                                  act_left, act_right, W_qc, bc, qh);
    k_attn<<<dim3(B_, H_), dim3(256), 0, stream>>>(qh, kvb, attn_in_w, attn_in_b, av_ws);
    k_ao2<<<dim3(8, 2), dim3(256), 0, stream>>>(av_ws, attn_out_w, attn_out_b, attn_o);
    k_syn<<<dim3(64, 2), dim3(256), 0, stream>>>(attn_o, act, syn_w, syn_b, ysyn);
    k_state<<<dim3(B_), dim3(256), 0, stream>>>(ysyn, syn_ln_g, syn_ln_b, state);
    k_nlm<<<dim3(N_), dim3(256), 0, stream>>>(trace, state, fc1_w, fc1_b, fc2_w, fc2_b,
                                              nlm_T, act);
    k_outf<<<dim3(25, 2), dim3(256), 0, stream>>>(act, aoR, boR, aoW, boW, r_o,
                                                  out_left, out_right, out_w, out_b,
                                                  (float*)d_out, t);
  }
  k_final<<<dim3(B_, T_), dim3(256), 0, stream>>>((float*)d_out);
}

// Round 10
// 3720.156 us; speedup vs baseline: 3.9001x; 1.2403x over previous
//
#include <hip/hip_runtime.h>
#include <hip/hip_bf16.h>
#include <math.h>

// SimplifiedCTM on MI355X — round 10:
// - k_attnf = sync + q-slice + attention + av in one kernel (grid 16x8).
// - k_syn/(ao2/outf) widened to cover all 256 CUs.
// - 32 patches/block in conv & kv GEMMs (weight re-reads halved).

#define DEV __device__ __forceinline__
typedef const float* fp;
typedef const float4* f4p;

#define B_   16
#define P_   196
#define D_   512
#define H_   8
#define HD_  64
#define N_   2048
#define M_   25
#define SA_  512
#define SO_  1024
#define O_   1000
#define T_   16

DEV float sigmf(float x){ return 1.0f / (1.0f + expf(-x)); }
DEV float wred(float v) { for (int m = 32; m; m >>= 1) v += __shfl_xor(v, m); return v; }
DEV float f4dot(float4 a, float4 b) { return a.x*b.x + a.y*b.y + a.z*b.z + a.w*b.w; }

DEV float breduce_sum(float v, float* red) {
  int t = threadIdx.x;
  red[t] = v; __syncthreads();
  for (int s = blockDim.x >> 1; s > 0; s >>= 1) {
    if (t < s) red[t] += red[t + s];
    __syncthreads();
  }
  float r = red[0]; __syncthreads();
  return r;
}
DEV float breduce_max(float v, float* red) {
  int t = threadIdx.x;
  red[t] = v; __syncthreads();
  for (int s = blockDim.x >> 1; s > 0; s >>= 1) {
    if (t < s) red[t] = fmaxf(red[t], red[t + s]);
    __syncthreads();
  }
  float r = red[0]; __syncthreads();
  return r;
}

// ---- P1a: conv-as-GEMM. grid (98 x 4). 32 patches staged (98.8KB LDS). ----
__global__ __launch_bounds__(256) void k_patch_mm(fp x, fp conv_w, fp conv_b, float* ptraw) {
  int pg = blockIdx.x >> 2, rg = blockIdx.x & 3;
  int bp0 = pg * 32;
  int tid = threadIdx.x, wave = tid >> 6, lane = tid & 63;
  __shared__ float patch[32][772];
  for (int pi = 0; pi < 32; pi++) {
    int bp = bp0 + pi, b = bp / P_, p = bp % P_;
    int ph = p / 14, pw = p % 14;
    for (int j = tid; j < 768; j += 256) {
      int ci = j >> 8, r = j & 255, qi = r >> 4, qj = r & 15;
      patch[pi][j] = x[((size_t)(b*3 + ci)*224 + (ph*16 + qi))*224 + (pw*16 + qj)];
    }
  }
  __syncthreads();
  for (int k = 0; k < 32; k++) {
    int r = rg*128 + wave*32 + k;
    const float* wr = conv_w + (size_t)r*768 + lane*4;
    float4 w0 = *(f4p)(wr), w1 = *(f4p)(wr + 256), w2 = *(f4p)(wr + 512);
    float cb = conv_b[r];
    for (int qtr = 0; qtr < 4; qtr++) {
      float pp[8];
      for (int pi = 0; pi < 8; pi++) {
        const float* pb = &patch[qtr*8 + pi][lane*4];
        pp[pi] = f4dot(w0, *(f4p)(pb)) + f4dot(w1, *(f4p)(pb + 256))
               + f4dot(w2, *(f4p)(pb + 512));
      }
      for (int pi = 0; pi < 8; pi++) {
        float s = wred(pp[pi]);
        if (lane == 0) ptraw[(size_t)(bp0 + qtr*8 + pi)*D_ + r] = s + cb;
      }
    }
  }
}

// ---- P1b: LN + pos (in-place). grid 196. ----
__global__ __launch_bounds__(256) void k_pln(float* pt, fp g, fp bb, fp pos) {
  int bp0 = blockIdx.x * 16;
  int tid = threadIdx.x, wave = tid >> 6, lane = tid & 63;
  for (int i = 0; i < 4; i++) {
    int bp = bp0 + wave*4 + i;
    int p = bp % P_;
    float* row = pt + (size_t)bp*D_;
    float4 v0 = *(f4p)(row + lane*8);
    float4 v1 = *(f4p)(row + lane*8 + 4);
    float s = v0.x+v0.y+v0.z+v0.w + v1.x+v1.y+v1.z+v1.w;
    float q = f4dot(v0,v0) + f4dot(v1,v1);
    s = wred(s); q = wred(q);
    float mu = s / (float)D_;
    float var = q / (float)D_ - mu*mu;
    float rstd = 1.f / sqrtf(var + 1e-5f);
    for (int j = 0; j < 8; j++) {
      int c = lane*8 + j;
      float v = (j < 4) ? ((const float*)&v0)[j] : ((const float*)&v1)[j-4];
      row[c] = (v - mu)*rstd*g[c] + bb[c] + pos[p*D_ + c];
    }
  }
}

// ---- P2a: kvraw = pt @ kv_w.T + kv_b. grid (98 x 4). 32 rows staged (66KB). ----
__global__ __launch_bounds__(256) void k_kv_mm(const float* pt, fp kv_w, fp kv_b, float* kvraw) {
  int pg = blockIdx.x >> 2, rg = blockIdx.x & 3;
  int bp0 = pg * 32;
  int tid = threadIdx.x, wave = tid >> 6, lane = tid & 63;
  __shared__ float xin[32][516];
  for (int idx = tid; idx < 32*512; idx += 256) {
    int bb = idx >> 9, c = idx & 511;
    xin[bb][c] = pt[(size_t)(bp0 + bb)*D_ + c];
  }
  __syncthreads();
  for (int k = 0; k < 32; k++) {
    int r = rg*128 + wave*32 + k;
    const float* wr = kv_w + (size_t)r*512 + lane*4;
    float4 w0 = *(f4p)(wr), w1 = *(f4p)(wr + 256);
    float kb = kv_b[r];
    for (int qtr = 0; qtr < 4; qtr++) {
      float pp[8];
      for (int pi = 0; pi < 8; pi++) {
        const float* pb = &xin[qtr*8 + pi][lane*4];
        pp[pi] = f4dot(w0, *(f4p)(pb)) + f4dot(w1, *(f4p)(pb + 256));
      }
      for (int pi = 0; pi < 8; pi++) {
        float s = wred(pp[pi]);
        if (lane == 0) kvraw[(size_t)(bp0 + qtr*8 + pi)*D_ + r] = s + kb;
      }
    }
  }
}

// ---- P2b: LN in-place. grid 196. ----
__global__ __launch_bounds__(256) void k_kvln(float* kv, fp g, fp bb) {
  int bp0 = blockIdx.x * 16;
  int tid = threadIdx.x, wave = tid >> 6, lane = tid & 63;
  for (int i = 0; i < 4; i++) {
    int bp = bp0 + wave*4 + i;
    float* row = kv + (size_t)bp*D_;
    float4 v0 = *(f4p)(row + lane*8);
    float4 v1 = *(f4p)(row + lane*8 + 4);
    float s = v0.x+v0.y+v0.z+v0.w + v1.x+v1.y+v1.z+v1.w;
    float q = f4dot(v0,v0) + f4dot(v1,v1);
    s = wred(s); q = wred(q);
    float mu = s / (float)D_;
    float var = q / (float)D_ - mu*mu;
    float rstd = 1.f / sqrtf(var + 1e-5f);
    for (int j = 0; j < 8; j++) {
      int c = lane*8 + j;
      float v = (j < 4) ? ((const float*)&v0)[j] : ((const float*)&v1)[j-4];
      row[c] = (v - mu)*rstd*g[c] + bb[c];
    }
  }
}

// ---- P3: W_qc = (wq @ q_w) * 0.125. grid (32,32). ----
__global__ __launch_bounds__(256) void k_wqc(fp aw, fp q_w, float* W_qc) {
  int i0 = blockIdx.x * 16, s0 = blockIdx.y * 16;
  int tid = threadIdx.x, il = tid >> 4, sl = tid & 15;
  __shared__ float s_wq[16][129];
  __shared__ float s_qw[128][17];
  float acc = 0.f;
  for (int kc = 0; kc < 4; kc++) {
    int k0 = kc * 128;
    for (int idx = tid; idx < 2048; idx += 256) {
      int r = idx >> 7, c = idx & 127;
      s_wq[r][c] = aw[(size_t)(i0 + r)*512 + k0 + c];
    }
    for (int idx = tid; idx < 2048; idx += 256) {
      int r = idx >> 4, c = idx & 15;
      s_qw[r][c] = q_w[(size_t)(k0 + r)*512 + s0 + c];
    }
    __syncthreads();
    for (int kk = 0; kk < 128; kk++)
      acc += s_wq[il][kk] * s_qw[kk][sl];
    __syncthreads();
  }
  W_qc[(size_t)(i0 + il)*512 + s0 + sl] = 0.125f * acc;
}

// ---- P3b: bc = 0.125 * (wq @ q_b + bq). grid 2. ----
__global__ __launch_bounds__(256) void k_wqcb(fp aw, fp q_b, fp ab, float* bc) {
  int i = blockIdx.x * 256 + threadIdx.x;
  float acc = ab[i];
  for (int j = 0; j < 512; j++) acc += aw[(size_t)i*512 + j] * q_b[j];
  bc[i] = 0.125f * acc;
}

// ---- INIT: state buffers (A-parity) + decay exp tables. ----
__global__ void k_init(fp start_state, fp start_trace, const int* oL, const int* oR,
                       fp decay_a, fp decay_o,
                       float* act, float* trace, float* aaA, float* baA,
                       float* aoA, float* boA, float* r_a, float* r_o) {
  int gid = blockIdx.x * 256 + threadIdx.x;
  if (gid < B_*N_*M_) {
    int bn = gid / M_, m = gid % M_;
    int n = bn % N_;
    trace[gid] = start_trace[n*M_ + m];
  }
  if (gid < B_*N_) act[gid] = start_state[gid & (N_-1)];
  if (gid < B_*SA_) { aaA[gid] = 0.f; baA[gid] = 0.f; }
  if (gid < B_*SO_) {
    int s = gid & (SO_-1);
    aoA[gid] = start_state[oL[s]] * start_state[oR[s]];
    boA[gid] = 1.0f;
  }
  if (gid < SA_) r_a[gid] = expf(-decay_a[gid]);
  if (gid < SO_) r_o[gid] = expf(-decay_o[gid]);
}

// ---- T1: fused sync + q-slice + attention + av. grid (16, 8). ----
__global__ __launch_bounds__(256) void k_attnf(const float* act, const float* aaR, const float* baR,
                                               float* aaW, float* baW, const float* r_a,
                                               const int* L, const int* R,
                                               const float* W_qc, const float* bc,
                                               const float* kvb, fp aw, fp ab, float* av_ws) {
  int b = blockIdx.x, h = blockIdx.y;
  int tid = threadIdx.x, wave = tid >> 6, lane = tid & 63;
  __shared__ float sact[512];
  __shared__ float qhh[64];
  __shared__ float qt[512];
  __shared__ float sc[256];
  __shared__ float red[256];
  __shared__ float zpart[4][512];
  __shared__ float zzL[512];
  // action sync (recomputed per block; h==0 persists)
  for (int cc = 0; cc < 2; cc++) {
    int s = tid + cc*256;
    float r = r_a[s];
    float pair = act[b*N_ + L[s]] * act[b*N_ + R[s]];
    float a  = r*aaR[b*SA_ + s] + pair;
    float bt = r*baR[b*SA_ + s] + 1.0f;
    if (h == 0) { aaW[b*SA_ + s] = a; baW[b*SA_ + s] = bt; }
    sact[s] = a / sqrtf(bt);
  }
  __syncthreads();
  // qh slice for this head: rows h*64..h*64+63 of W_qc
  for (int k = 0; k < 16; k++) {
    int r = h*HD_ + wave*16 + k;
    const float* wr = W_qc + (size_t)r*512 + lane*4;
    float s = f4dot(*(f4p)(wr),       *(f4p)(&sact[lane*4]))
            + f4dot(*(f4p)(wr + 256), *(f4p)(&sact[lane*4 + 256]));
    s = wred(s);
    if (lane == 0) qhh[wave*16 + k] = s + bc[r];
  }
  __syncthreads();
  // qt = qh_h @ wk_h (column-parallel)
  float acc0 = 0.f, acc1 = 0.f;
  for (int e = 0; e < HD_; e++) {
    float q = qhh[e];
    const float* ar = aw + (size_t)(512 + h*HD_ + e)*D_;
    acc0 += q * ar[tid];
    acc1 += q * ar[tid + 256];
  }
  qt[tid] = acc0; qt[tid + 256] = acc1;
  float kb = 0.f;
  for (int e = 0; e < HD_; e++) kb += qhh[e] * ab[512 + h*HD_ + e];
  __syncthreads();
  // scores
  for (int p = wave*49; p < wave*49 + 49; p++) {
    const float* kvp = kvb + ((size_t)(b*P_ + p))*D_;
    float s = f4dot(*(f4p)(kvp + lane*4),       *(f4p)(qt + lane*4))
            + f4dot(*(f4p)(kvp + 256 + lane*4), *(f4p)(qt + 256 + lane*4));
    s = wred(s);
    if (lane == 0) sc[p] = s + kb;
  }
  __syncthreads();
  float v = (tid < P_) ? sc[tid] : -1e30f;
  float m = breduce_max(v, red);
  float e = (tid < P_) ? expf(sc[tid] - m) : 0.f;
  if (tid < P_) sc[tid] = e;
  float ssum = breduce_sum(e, red);
  float inv = 1.f / ssum;
  // zz
  float4 z0 = {0,0,0,0}, z1 = {0,0,0,0};
  for (int p = wave*49; p < wave*49 + 49; p++) {
    const float* kvp = kvb + ((size_t)(b*P_ + p))*D_ + lane*8;
    float w = sc[p];
    float4 a = *(f4p)(kvp), c = *(f4p)(kvp + 4);
    z0.x += w*a.x; z0.y += w*a.y; z0.z += w*a.z; z0.w += w*a.w;
    z1.x += w*c.x; z1.y += w*c.y; z1.z += w*c.z; z1.w += w*c.w;
  }
  *(float4*)(&zpart[wave][lane*8])     = z0;
  *(float4*)(&zpart[wave][lane*8 + 4]) = z1;
  __syncthreads();
  for (int cc = 0; cc < 2; cc++) {
    int c = tid + cc*256;
    zzL[c] = (zpart[0][c] + zpart[1][c] + zpart[2][c] + zpart[3][c]) * inv;
  }
  __syncthreads();
  // av for this head
  for (int k = 0; k < 16; k++) {
    int e2 = wave*16 + k;
    int r = 1024 + h*HD_ + e2;
    const float* wr = aw + (size_t)r*512 + lane*4;
    float s = f4dot(*(f4p)(wr),       *(f4p)(&zzL[lane*4]))
            + f4dot(*(f4p)(wr + 256), *(f4p)(&zzL[lane*4 + 256]));
    s = wred(s);
    if (lane == 0) av_ws[b*D_ + h*HD_ + e2] = s + ab[r];
  }
}

// ---- T2c: attn_o = av @ ow.T + ob. grid (16,2): 32 rows/block. ----
__global__ __launch_bounds__(256) void k_ao2(const float* av_ws, fp ow, fp ob, float* attn_o) {
  int rb = blockIdx.x, bg = blockIdx.y;
  int tid = threadIdx.x, wave = tid >> 6, lane = tid & 63;
  __shared__ float s_a[8][516];
  for (int idx = tid; idx < 8*512; idx += 256) {
    int bb = idx >> 9, c = idx & 511;
    s_a[bb][c] = av_ws[(bg*8 + bb)*D_ + c];
  }
  __syncthreads();
  for (int k = 0; k < 8; k++) {
    int r = rb*32 + wave*8 + k;
    const float* wr = ow + (size_t)r*512 + lane*4;
    float4 w0 = *(f4p)(wr), w1 = *(f4p)(wr + 256);
    float pp[8];
    for (int bb = 0; bb < 8; bb++) {
      const float* pb = &s_a[bb][lane*4];
      pp[bb] = f4dot(w0, *(f4p)(pb)) + f4dot(w1, *(f4p)(pb + 256));
    }
    float obr = ob[r];
    for (int bb = 0; bb < 8; bb++) {
      float s = wred(pp[bb]);
      if (lane == 0) attn_o[(bg*8 + bb)*D_ + r] = s + obr;
    }
  }
}

// ---- T3: y = pre @ syn_w.T + syn_b. grid (128,2): 32 rows/block. ----
__global__ __launch_bounds__(256) void k_syn(const float* attn_o, const float* act,
                                             fp syn_w, fp syn_b, float* y) {
  int rb = blockIdx.x, bg = blockIdx.y;
  int tid = threadIdx.x, wave = tid >> 6, lane = tid & 63;
  __shared__ float pre8[8][2560];
  for (int bb = 0; bb < 8; bb++) {
    int b = bg*8 + bb;
    for (int i = tid; i < 2560; i += 256)
      pre8[bb][i] = (i < 512) ? attn_o[b*D_ + i] : act[b*N_ + (i - 512)];
  }
  __syncthreads();
  for (int k = 0; k < 8; k++) {
    int r = rb*32 + wave*8 + k;
    const float* wr = syn_w + (size_t)r*2560 + lane*4;
    float4 wreg[10];
    for (int j = 0; j < 10; j++) wreg[j] = *(f4p)(wr + j*256);
    float pp[8] = {0,0,0,0,0,0,0,0};
    for (int j = 0; j < 10; j++) {
      int idx = lane*4 + j*256;
      for (int bb = 0; bb < 8; bb++)
        pp[bb] += f4dot(wreg[j], *(f4p)(&pre8[bb][idx]));
    }
    float sb = syn_b[r];
    for (int bb = 0; bb < 8; bb++) {
      float s = wred(pp[bb]);
      if (lane == 0) y[(size_t)(bg*8 + bb)*4096 + r] = s + sb;
    }
  }
}

// ---- T4: GLU + LN -> state. grid 16. ----
__global__ __launch_bounds__(256) void k_state(const float* y, fp g, fp bvec, float* state) {
  int b = blockIdx.x, tid = threadIdx.x;
  __shared__ float st[2048];
  __shared__ float red[256];
  float ls = 0.f, lq = 0.f;
  for (int ii = 0; ii < 8; ii++) {
    int c = ii*256 + tid;
    float a  = y[(size_t)b*4096 + c];
    float gg = y[(size_t)b*4096 + 2048 + c];
    float v = a * sigmf(gg);
    st[c] = v; ls += v; lq += v*v;
  }
  float S = breduce_sum(ls, red);
  float Q = breduce_sum(lq, red);
  float mu = S / (float)N_;
  float var = Q / (float)N_ - mu*mu;
  float rstd = 1.f / sqrtf(var + 1e-5f);
  for (int ii = 0; ii < 8; ii++) {
    int c = ii*256 + tid;
    state[b*N_ + c] = (st[c] - mu)*rstd*g[c] + bvec[c];
  }
}

// ---- T5: NLM per neuron; trace shift fused. grid 2048. ----
__global__ __launch_bounds__(256) void k_nlm(float* trace, const float* state,
                                             fp fc1_w, fp fc1_b, fp fc2_w, fp fc2_b,
                                             fp nlmT, float* act) {
  int n = blockIdx.x, tid = threadIdx.x;
  __shared__ float tr[B_][M_];
  __shared__ float uu[256][17];
  __shared__ float h1[128][17];
  __shared__ float vout[B_][2];
  for (int i = tid; i < B_*M_; i += 256) {
    int b = i / M_, m = i % M_;
    tr[b][m] = (m < M_-1) ? trace[((size_t)(b*N_ + n))*M_ + m + 1] : state[b*N_ + n];
  }
  __syncthreads();
  for (int i = tid; i < B_*M_; i += 256) {
    int b = i / M_, m = i % M_;
    trace[((size_t)(b*N_ + n))*M_ + m] = tr[b][m];
  }
  float w25[M_];
  for (int m = 0; m < M_; m++) w25[m] = fc1_w[((size_t)n*M_ + m)*256 + tid];
  float bias = fc1_b[n*256 + tid];
  for (int b = 0; b < B_; b++) {
    float u = bias;
    for (int m = 0; m < M_; m++) u += tr[b][m]*w25[m];
    uu[tid][b] = u;
  }
  __syncthreads();
  if (tid < 128) {
    for (int b = 0; b < B_; b++)
      h1[tid][b] = uu[tid][b] * sigmf(uu[tid + 128][b]);
  }
  __syncthreads();
  if (tid < 32) {
    int b = tid >> 1, o = tid & 1;
    float acc = fc2_b[n*2 + o];
    for (int hh = 0; hh < 128; hh++) acc += h1[hh][b] * fc2_w[((size_t)n*128 + hh)*2 + o];
    vout[b][o] = acc;
  }
  __syncthreads();
  if (tid < B_) {
    act[tid*N_ + n] = vout[tid][0] * sigmf(vout[tid][1]) / nlmT[0];
  }
}

// ---- T6: fused out-sync + preds GEMV. grid (50,2): 20 rows/block. ----
__global__ __launch_bounds__(256) void k_outf(const float* act, const float* aoR, const float* boR,
                                              float* aoW, float* boW, const float* r_o,
                                              const int* L, const int* R,
                                              fp out_w, fp out_b, float* out, int t) {
  int rb = blockIdx.x, bg = blockIdx.y;
  int tid = threadIdx.x, wave = tid >> 6, lane = tid & 63;
  __shared__ float s_sout[8][1024];
  for (int i = 0; i < 32; i++) {
    int idx = tid + i*256;
    int bb = idx >> 10, s = idx & 1023;
    int b = bg*8 + bb;
    float r = r_o[s];
    float pair = act[b*N_ + L[s]] * act[b*N_ + R[s]];
    float a  = r*aoR[b*SO_ + s] + pair;
    float bt = r*boR[b*SO_ + s] + 1.f;
    if (rb == 0) { aoW[b*SO_ + s] = a; boW[b*SO_ + s] = bt; }
    s_sout[bb][s] = a / sqrtf(bt);
  }
  __syncthreads();
  for (int k = 0; k < 5; k++) {
    int r = rb*20 + wave*5 + k;
    const float* wr = out_w + (size_t)r*1024 + lane*4;
    float4 w0 = *(f4p)(wr),       w1 = *(f4p)(wr + 256),
           w2 = *(f4p)(wr + 512), w3 = *(f4p)(wr + 768);
    float pp[8];
    for (int bb = 0; bb < 8; bb++) {
      const float* pb = &s_sout[bb][lane*4];
      pp[bb] = f4dot(w0, *(f4p)(pb))       + f4dot(w1, *(f4p)(pb + 256))
             + f4dot(w2, *(f4p)(pb + 512)) + f4dot(w3, *(f4p)(pb + 768));
    }
    float obr = out_b[r];
    for (int bb = 0; bb < 8; bb++) {
      float s = wred(pp[bb]);
      if (lane == 0) out[((size_t)((bg*8 + bb)*O_ + r))*T_ + t] = s + obr;
    }
  }
}

// ---- T7: entropy. grid (16,16). ----
__global__ __launch_bounds__(256) void k_final(float* out) {
  int b = blockIdx.x, t = blockIdx.y, tid = threadIdx.x;
  __shared__ float red[256];
  float lm = -1e30f;
  for (int o = tid; o < O_; o += 256) lm = fmaxf(lm, out[((size_t)(b*O_ + o))*T_ + t]);
  float Mx = breduce_max(lm, red);
  float le = 0.f;
  for (int o = tid; o < O_; o += 256) le += expf(out[((size_t)(b*O_ + o))*T_ + t] - Mx);
  float S = breduce_sum(le, red);
  float lt = 0.f;
  for (int o = tid; o < O_; o += 256) {
    float pr = expf(out[((size_t)(b*O_ + o))*T_ + t] - Mx) / S;
    lt += pr * logf(pr + 1e-10f);
  }
  float E = breduce_sum(lt, red);
  if (tid == 0)
    out[(size_t)B_*O_*T_ + b*T_ + t] = -E / logf((float)O_);
}

extern "C" void kernel_launch(void* const* d_in, const int* in_sizes, int n_in,
                              void* d_out, int out_size, void* d_ws, size_t ws_size,
                              hipStream_t stream) {
  (void)in_sizes; (void)n_in; (void)out_size; (void)ws_size;
  fp x          = (fp)d_in[0];
  fp conv_w     = (fp)d_in[1];
  fp conv_b     = (fp)d_in[2];
  fp patch_ln_g = (fp)d_in[3];
  fp patch_ln_b = (fp)d_in[4];
  fp pos        = (fp)d_in[5];
  fp kv_w       = (fp)d_in[6];
  fp kv_b       = (fp)d_in[7];
  fp kv_ln_g    = (fp)d_in[8];
  fp kv_ln_b    = (fp)d_in[9];
  fp q_w        = (fp)d_in[10];
  fp q_b        = (fp)d_in[11];
  fp attn_in_w  = (fp)d_in[12];
  fp attn_in_b  = (fp)d_in[13];
  fp attn_out_w = (fp)d_in[14];
  fp attn_out_b = (fp)d_in[15];
  fp syn_w      = (fp)d_in[16];
  fp syn_b      = (fp)d_in[17];
  fp syn_ln_g   = (fp)d_in[18];
  fp syn_ln_b   = (fp)d_in[19];
  fp fc1_w      = (fp)d_in[20];
  fp fc1_b      = (fp)d_in[21];
  fp fc2_w      = (fp)d_in[22];
  fp fc2_b      = (fp)d_in[23];
  fp nlm_T      = (fp)d_in[24];
  fp start_state= (fp)d_in[25];
  fp start_trace= (fp)d_in[26];
  fp decay_a    = (fp)d_in[27];
  fp decay_o    = (fp)d_in[28];
  fp out_w      = (fp)d_in[29];
  fp out_b      = (fp)d_in[30];
  const int* act_left  = (const int*)d_in[31];
  const int* act_right = (const int*)d_in[32];
  const int* out_left  = (const int*)d_in[33];
  const int* out_right = (const int*)d_in[34];

  // Region X [0, 1605632) holds pt during precompute, then per-tick state.
  float* ws = (float*)d_ws;
  float* pt     = ws;                          // precompute only
  float* act    = ws + 0;                      // 32768
  float* trace  = ws + 32768;                  // 819200 -> 851968
  float* aaA    = ws + 851968;                 // 8192
  float* aaB    = ws + 860160;                 // 8192
  float* baA    = ws + 868352;                 // 8192
  float* baB    = ws + 876544;                 // 8192 -> 884736
  float* aoA    = ws + 884736;                 // 16384
  float* aoB    = ws + 901120;                 // 16384
  float* boA    = ws + 917504;                 // 16384
  float* boB    = ws + 933888;                 // 16384 -> 950272
  float* attn_o = ws + 958464;                 // 8192
  float* ysyn   = ws + 966656;                 // 65536 -> 1032192
  float* state  = ws + 1032192;                // 32768
  float* av_ws  = ws + 1064960;                // 8192
  float* r_a    = ws + 1073152;                // 512
  float* r_o    = ws + 1073664;                // 1024 -> 1074688
  float* W_qc   = ws + 1074688;                // 262144 -> 1336832
  float* bc     = ws + 1336832;                // 512 -> 1337344 < 1605632
  float* kvb    = ws + 1605632;                // 1605632

  k_patch_mm<<<dim3(98*4), dim3(256), 0, stream>>>(x, conv_w, conv_b, pt);
  k_pln<<<dim3(196), dim3(256), 0, stream>>>(pt, patch_ln_g, patch_ln_b, pos);
  k_kv_mm<<<dim3(98*4), dim3(256), 0, stream>>>(pt, kv_w, kv_b, kvb);
  k_kvln<<<dim3(196), dim3(256), 0, stream>>>(kvb, kv_ln_g, kv_ln_b);
  // pt dead; safe to write W_qc / state region now.
  k_wqc<<<dim3(32, 32), dim3(256), 0, stream>>>(attn_in_w, q_w, W_qc);
  k_wqcb<<<dim3(2), dim3(256), 0, stream>>>(attn_in_w, q_b, attn_in_b, bc);
  k_init<<<dim3((B_*N_*M_ + 255)/256), dim3(256), 0, stream>>>(start_state, start_trace,
        out_left, out_right, decay_a, decay_o, act, trace, aaA, baA, aoA, boA, r_a, r_o);

  for (int t = 0; t < T_; t++) {
    float* aaR = (t & 1) ? aaB : aaA;  float* aaW = (t & 1) ? aaA : aaB;
    float* baR = (t & 1) ? baB : baA;  float* baW = (t & 1) ? baA : baB;
    float* aoR = (t & 1) ? aoB : aoA;  float* aoW = (t & 1) ? aoA : aoB;
    float* boR = (t & 1) ? boB : boA;  float* boW = (t & 1) ? boA : boB;
    k_attnf<<<dim3(B_, H_), dim3(256), 0, stream>>>(act, aaR, baR, aaW, baW, r_a,
                                                    act_left, act_right, W_qc, bc,
                                                    kvb, attn_in_w, attn_in_b, av_ws);
    k_ao2<<<dim3(16, 2), dim3(256), 0, stream>>>(av_ws, attn_out_w, attn_out_b, attn_o);
    k_syn<<<dim3(128, 2), dim3(256), 0, stream>>>(attn_o, act, syn_w, syn_b, ysyn);
    k_state<<<dim3(B_), dim3(256), 0, stream>>>(ysyn, syn_ln_g, syn_ln_b, state);
    k_nlm<<<dim3(N_), dim3(256), 0, stream>>>(trace, state, fc1_w, fc1_b, fc2_w, fc2_b,
                                              nlm_T, act);
    k_outf<<<dim3(50, 2), dim3(256), 0, stream>>>(act, aoR, boR, aoW, boW, r_o,
                                                  out_left, out_right, out_w, out_b,
                                                  (float*)d_out, t);
  }
  k_final<<<dim3(B_, T_), dim3(256), 0, stream>>>((float*)d_out);
}